// Round 1
// baseline (530.682 us; speedup 1.0000x reference)
//
#include <hip/hip_runtime.h>
#include <hip/hip_bf16.h>
#include <math.h>

#define HID 128
#define NHEAD 4
#define CH 32
#define NLAYER 3
#define EDIM 3
#define EPSLN 1e-5f
#define SLOPE 0.2f
#define RSLOTS 4096   // LN-reduction slots (pairs); 32 KB
#define PAD_W -1e30f  // additive sentinel: exp(part + PAD_W) == 0

typedef __bf16 bf16x8 __attribute__((ext_vector_type(8)));
typedef float f32x4 __attribute__((ext_vector_type(4)));

__device__ __forceinline__ float bflo(unsigned d) { return __uint_as_float(d << 16); }
__device__ __forceinline__ float bfhi(unsigned d) { return __uint_as_float(d & 0xffff0000u); }

// ---------------------------------------------------------------- degree count
__global__ void k_count(const int* __restrict__ dst, int* __restrict__ deg, int E) {
    int i = blockIdx.x * blockDim.x + threadIdx.x;
    if (i < E) atomicAdd(&deg[dst[i]], 1);
}

// ---------------------------------------------------------------- single-block scan
__global__ __launch_bounds__(1024) void k_scan(const int* __restrict__ in,
                                               int* __restrict__ outs,
                                               int* __restrict__ outc, int n) {
    __shared__ int sw[16];
    __shared__ int scarry;
    int tid = threadIdx.x, lane = tid & 63, wid = tid >> 6;
    if (tid == 0) scarry = 0;
    __syncthreads();
    for (int base = 0; base < n; base += 1024) {
        int i = base + tid;
        int v = (i < n) ? in[i] : 0;
        int x = v;
#pragma unroll
        for (int o = 1; o < 64; o <<= 1) { int y = __shfl_up(x, o, 64); if (lane >= o) x += y; }
        if (lane == 63) sw[wid] = x;
        __syncthreads();
        int carry = scarry;
        if (tid < 16) {
            int s = sw[tid];
#pragma unroll
            for (int o = 1; o < 16; o <<= 1) { int y = __shfl_up(s, o, 64); if (tid >= o) s += y; }
            sw[tid] = s;
        }
        __syncthreads();
        int wofs = (wid == 0) ? 0 : sw[wid - 1];
        int incl = carry + wofs + x;
        if (i < n) { outs[i] = incl - v; outc[i] = incl - v; }
        __syncthreads();
        if (tid == 0) scarry = carry + sw[15];
        __syncthreads();
    }
    if (tid == 0) outs[n] = scarry;
}

// ---------------------------------------------------------------- group prep (unsorted)
__global__ void k_group(const int* __restrict__ deg, int* __restrict__ g4, int G, int N) {
    int g = blockIdx.x * blockDim.x + threadIdx.x;
    if (g < G) {
        int m = 0;
#pragma unroll
        for (int j = 0; j < 4; j++) {
            int n = 4 * g + j;
            if (n < N) m = max(m, deg[n]);
        }
        g4[g] = 4 * m;
    }
}

__global__ void k_nodebase(const int* __restrict__ groupstart,
                           int* __restrict__ slotbase, int N) {
    int i = blockIdx.x * blockDim.x + threadIdx.x;
    if (i < N) slotbase[i] = groupstart[i >> 2] + (i & 3);
}

__global__ void k_padinit(int* __restrict__ srcs, float4* __restrict__ ea4,
                          const int* __restrict__ groupstart, int G) {
    int total = groupstart[G];
    for (int i = blockIdx.x * blockDim.x + threadIdx.x; i < total; i += gridDim.x * blockDim.x) {
        srcs[i] = 0;
        ea4[i] = make_float4(0.f, 0.f, 0.f, PAD_W);
    }
}

__global__ void k_fill2(const int* __restrict__ src, const int* __restrict__ dst,
                        const float* __restrict__ eattr, int* __restrict__ cursor,
                        const int* __restrict__ slotbase, int* __restrict__ srcs,
                        float4* __restrict__ ea4, int E) {
    int i = blockIdx.x * blockDim.x + threadIdx.x;
    if (i < E) {
        int n = dst[i];
        int pos = atomicAdd(&cursor[n], 1);
        int slot = slotbase[n] + 4 * pos;
        srcs[slot] = src[i];
        ea4[slot] = make_float4(eattr[3 * i], eattr[3 * i + 1], eattr[3 * i + 2], 0.f);
    }
}

// ---------------------------------------------------------------- weight prep
// bf16 + MFMA B-fragment swizzle: wz[((s*8+n)*64+q)*8+j] = W[(s*32+(q>>4)*8+j)*128 + n*16+(q&15)]
__global__ __launch_bounds__(256) void k_wprep(const float* __restrict__ Wl,
                                               const float* __restrict__ Wr,
                                               const float* __restrict__ Wout,
                                               __hip_bfloat16* __restrict__ wz) {
    int b = blockIdx.x;  // 0..6: l0Wl,l0Wr,l1Wl,l1Wr,l2Wl,l2Wr,Wout
    const float* src = (b < 6) ? ((b & 1) ? Wr + (size_t)(b >> 1) * 16384
                                          : Wl + (size_t)(b >> 1) * 16384)
                               : Wout;
    for (int t = threadIdx.x; t < 16384; t += 256) {
        int j = t & 7, q = (t >> 3) & 63, n = (t >> 9) & 7, s = t >> 12;
        int k = s * 32 + (q >> 4) * 8 + j;
        int c = n * 16 + (q & 15);
        wz[(size_t)b * 16384 + t] = __float2bfloat16(src[k * 128 + c]);
    }
}

__global__ __launch_bounds__(256) void k_cast(const float* __restrict__ in,
                                              __hip_bfloat16* __restrict__ out, int n) {
    int i = (blockIdx.x * 256 + threadIdx.x) * 4;
    if (i < n) {
        float4 v = *(const float4*)&in[i];
        __hip_bfloat16 o[4] = {__float2bfloat16(v.x), __float2bfloat16(v.y),
                               __float2bfloat16(v.z), __float2bfloat16(v.w)};
        *(ushort4*)&out[i] = *(ushort4*)o;
    }
}

// ---------------------------------------------------------------- MFMA GEMM
// Y = Xb(bf16) @ W(bf16 pre-swizzled); out bf16 (layers) or fp32+bias (final).
template <bool BF16OUT>
__global__ __launch_bounds__(256) void k_gemm_mfma(const __hip_bfloat16* __restrict__ Xb,
                                                   const __hip_bfloat16* __restrict__ Wz0,
                                                   const __hip_bfloat16* __restrict__ Wz1,
                                                   void* __restrict__ Y0v,
                                                   void* __restrict__ Y1v,
                                                   const float* __restrict__ bias, int N) {
    __shared__ __hip_bfloat16 sW[16384];  // 32 KB
    const __hip_bfloat16* Wz = blockIdx.y ? Wz1 : Wz0;
    void* Yv = blockIdx.y ? Y1v : Y0v;
    int tid = threadIdx.x;
    {
        const float4* s4 = (const float4*)Wz;
        float4* d4 = (float4*)sW;
#pragma unroll
        for (int i = 0; i < 8; i++) d4[tid + 256 * i] = s4[tid + 256 * i];
    }
    __syncthreads();

    int wv = tid >> 6, lane = tid & 63;
    int quad = lane >> 4, l16 = lane & 15;
    int mbase = blockIdx.x * 128 + wv * 32;

    f32x4 acc[2][8];
#pragma unroll
    for (int mt = 0; mt < 2; mt++)
#pragma unroll
        for (int n = 0; n < 8; n++) acc[mt][n] = (f32x4){0.f, 0.f, 0.f, 0.f};

#pragma unroll
    for (int s = 0; s < 4; s++) {
        bf16x8 a[2];
#pragma unroll
        for (int mt = 0; mt < 2; mt++) {
            int row = mbase + mt * 16 + l16;
            row = (row < N) ? row : (N - 1);
            a[mt] = *(const bf16x8*)&Xb[(size_t)row * HID + s * 32 + quad * 8];
        }
#pragma unroll
        for (int n = 0; n < 8; n++) {
            bf16x8 b = *(const bf16x8*)&sW[((s * 8 + n) * 64 + lane) * 8];
            acc[0][n] = __builtin_amdgcn_mfma_f32_16x16x32_bf16(a[0], b, acc[0][n], 0, 0, 0);
            acc[1][n] = __builtin_amdgcn_mfma_f32_16x16x32_bf16(a[1], b, acc[1][n], 0, 0, 0);
        }
    }

    float bv[8];
#pragma unroll
    for (int n = 0; n < 8; n++) bv[n] = bias ? bias[n * 16 + l16] : 0.f;

#pragma unroll
    for (int mt = 0; mt < 2; mt++)
#pragma unroll
        for (int reg = 0; reg < 4; reg++) {
            int row = mbase + mt * 16 + quad * 4 + reg;
            if (row < N) {
                if (BF16OUT) {
                    __hip_bfloat16* yp = (__hip_bfloat16*)Yv + (size_t)row * HID + l16;
#pragma unroll
                    for (int n = 0; n < 8; n++) yp[n * 16] = __float2bfloat16(acc[mt][n][reg]);
                } else {
                    float* yp = (float*)Yv + (size_t)row * HID + l16;
#pragma unroll
                    for (int n = 0; n < 8; n++) yp[n * 16] = acc[mt][n][reg] + bv[n];
                }
            }
        }
}

// ---------------------------------------------------------------- GATv2 aggregate
// bf16 xl/xr (exact unpack via shifts), fp32 math, packed-bf16 tmp out.
__global__ __launch_bounds__(256) void k_aggregate(const __hip_bfloat16* __restrict__ xlb,
                                                   const __hip_bfloat16* __restrict__ xrb,
                                                   const int* __restrict__ srcs,
                                                   const float4* __restrict__ ea4,
                                                   const int* __restrict__ groupstart,
                                                   const float* __restrict__ We,
                                                   const float* __restrict__ att,
                                                   unsigned* __restrict__ tmpp,
                                                   float* __restrict__ red, int N, int G) {
    int wid = threadIdx.x >> 6;
    int lane = threadIdx.x & 63;
    int g = blockIdx.x * 4 + wid;
    if (g >= G) return;
    int c0 = lane * 2;
    int head = lane >> 4;

    float we00 = We[c0], we01 = We[c0 + 1];
    float we10 = We[HID + c0], we11 = We[HID + c0 + 1];
    float we20 = We[2 * HID + c0], we21 = We[2 * HID + c0 + 1];
    float at0 = att[head * CH + (c0 & 31)];
    float at1 = att[head * CH + (c0 & 31) + 1];

    int base = __builtin_amdgcn_readfirstlane(groupstart[g]);
    int steps = __builtin_amdgcn_readfirstlane(groupstart[g + 1] - base) >> 2;

    float2 xrv[4];
#pragma unroll
    for (int j = 0; j < 4; j++) {
        int node = 4 * g + j;
        node = (node < N) ? node : (N - 1);
        unsigned d = *(const unsigned*)&xrb[(size_t)node * HID + c0];
        xrv[j] = make_float2(bflo(d), bfhi(d));
    }

    float l[4] = {0.f, 0.f, 0.f, 0.f};
    float A0[4] = {0.f, 0.f, 0.f, 0.f};
    float A1[4] = {0.f, 0.f, 0.f, 0.f};

    const int4* sp = (const int4*)(srcs + base);
    const float4* ep = ea4 + base;

    for (int t = 0; t < steps; t++) {
        int4 s4 = sp[t];
        int s[4] = {s4.x, s4.y, s4.z, s4.w};
        float4 ev[4];
#pragma unroll
        for (int j = 0; j < 4; j++) ev[j] = ep[4 * t + j];
        unsigned dv[4];
#pragma unroll
        for (int j = 0; j < 4; j++)
            dv[j] = *(const unsigned*)&xlb[(size_t)s[j] * HID + c0];  // 4 indep gathers, 4B each
#pragma unroll
        for (int j = 0; j < 4; j++) {
            float xv0 = bflo(dv[j]), xv1 = bfhi(dv[j]);
            float m0 = xv0 + xrv[j].x + fmaf(ev[j].x, we00, fmaf(ev[j].y, we10, ev[j].z * we20));
            float m1 = xv1 + xrv[j].y + fmaf(ev[j].x, we01, fmaf(ev[j].y, we11, ev[j].z * we21));
            m0 = (m0 > 0.f) ? m0 : SLOPE * m0;
            m1 = (m1 > 0.f) ? m1 : SLOPE * m1;
            float part = fmaf(m0, at0, m1 * at1);
            part += __shfl_xor(part, 1);
            part += __shfl_xor(part, 2);
            part += __shfl_xor(part, 4);
            part += __shfl_xor(part, 8);
            float p = __expf(part + ev[j].w);  // padding: exp(-1e30)=0
            l[j] += p;
            A0[j] = fmaf(p, xv0, A0[j]);
            A1[j] = fmaf(p, xv1, A1[j]);
        }
    }

    float ssum = 0.f, ssq = 0.f;
#pragma unroll
    for (int j = 0; j < 4; j++) {
        int node = 4 * g + j;
        if (node < N) {
            float inv = 1.f / (l[j] + 1e-16f);
            float o0 = A0[j] * inv, o1 = A1[j] * inv;
            __hip_bfloat16 pk[2] = {__float2bfloat16(o0), __float2bfloat16(o1)};
            tmpp[(size_t)node * (HID / 2) + lane] = *(unsigned*)pk;
            ssum += o0 + o1;                 // LN stats from pre-rounded fp32
            ssq += fmaf(o0, o0, o1 * o1);
        }
    }
#pragma unroll
    for (int o = 32; o >= 1; o >>= 1) { ssum += __shfl_xor(ssum, o); ssq += __shfl_xor(ssq, o); }
    if (lane == 0) {
        int slot = (g & (RSLOTS - 1)) * 2;
        atomicAdd(&red[slot], ssum);
        atomicAdd(&red[slot + 1], ssq);
    }
}

// ---------------------------------------------------------------- LN finish (also re-zeros red)
__global__ __launch_bounds__(256) void k_finish(float* __restrict__ red,
                                                float* __restrict__ scal, float M) {
    __shared__ float ls[8];
    int tid = threadIdx.x;
    float s = 0.f, q = 0.f;
    for (int i = tid; i < RSLOTS; i += 256) { s += red[2 * i]; q += red[2 * i + 1]; }
#pragma unroll
    for (int o = 32; o >= 1; o >>= 1) { s += __shfl_xor(s, o); q += __shfl_xor(q, o); }
    if ((tid & 63) == 0) { ls[(tid >> 6) * 2] = s; ls[(tid >> 6) * 2 + 1] = q; }
    __syncthreads();
    if (tid == 0) {
        float S = ls[0] + ls[2] + ls[4] + ls[6];
        float Q = ls[1] + ls[3] + ls[5] + ls[7];
        float mean = S / M;
        float var = Q / M - mean * mean;
        scal[0] = mean;
        scal[1] = rsqrtf(var + EPSLN);
    }
    // re-zero for the next layer (next aggregate sees zeros via kernel boundary)
    for (int i = tid; i < RSLOTS * 2; i += 256) red[i] = 0.f;
}

// ---------------------------------------------------------------- LN + gelu (bf16 in/out)
__global__ __launch_bounds__(256) void k_ln_gelu(const uint4* __restrict__ in4,
                                                 const float* __restrict__ w,
                                                 const float* __restrict__ b,
                                                 const float* __restrict__ scal,
                                                 uint4* __restrict__ out4, int n8) {
    int i = blockIdx.x * blockDim.x + threadIdx.x;
    if (i >= n8) return;
    float mean = scal[0], inv = scal[1];
    uint4 v = in4[i];
    int col = (i * 8) & 127;
    float4 w0 = *(const float4*)&w[col], w1 = *(const float4*)&w[col + 4];
    float4 b0 = *(const float4*)&b[col], b1 = *(const float4*)&b[col + 4];
    float r[8] = {bflo(v.x), bfhi(v.x), bflo(v.y), bfhi(v.y),
                  bflo(v.z), bfhi(v.z), bflo(v.w), bfhi(v.w)};
    float wr[8] = {w0.x, w0.y, w0.z, w0.w, w1.x, w1.y, w1.z, w1.w};
    float br[8] = {b0.x, b0.y, b0.z, b0.w, b1.x, b1.y, b1.z, b1.w};
    __hip_bfloat16 o[8];
#pragma unroll
    for (int j = 0; j < 8; j++) {
        float t = fmaf((r[j] - mean) * inv, wr[j], br[j]);
        o[j] = __float2bfloat16(0.5f * t * (1.f + erff(t * 0.70710678118654752f)));
    }
    out4[i] = *(uint4*)o;
}

// ---------------------------------------------------------------- launch
extern "C" void kernel_launch(void* const* d_in, const int* in_sizes, int n_in,
                              void* d_out, int out_size, void* d_ws, size_t ws_size,
                              hipStream_t stream) {
    const float* x = (const float*)d_in[0];
    const int* ei = (const int*)d_in[1];
    const float* eattr = (const float*)d_in[2];
    const float* Wl = (const float*)d_in[3];
    const float* Wr = (const float*)d_in[4];
    const float* We = (const float*)d_in[5];
    const float* att = (const float*)d_in[6];
    const float* lnw = (const float*)d_in[7];
    const float* lnb = (const float*)d_in[8];
    const float* Wout = (const float*)d_in[9];
    const float* bout = (const float*)d_in[10];
    float* out = (float*)d_out;

    int N = in_sizes[0] / HID;
    int E = in_sizes[1] / 2;
    int G = (N + 3) / 4;
    int SCAP = E + 8 * N;
    const int* src = ei;
    const int* dst = ei + E;

    char* w = (char*)d_ws;
    __hip_bfloat16* hb = (__hip_bfloat16*)w;   w += (size_t)N * HID * 2;
    __hip_bfloat16* xlb = (__hip_bfloat16*)w;  w += (size_t)N * HID * 2;
    __hip_bfloat16* xrb = (__hip_bfloat16*)w;  w += (size_t)N * HID * 2;
    unsigned* tmpp = (unsigned*)w;             w += (size_t)N * HID * 2;
    __hip_bfloat16* wz = (__hip_bfloat16*)w;   w += (size_t)7 * 16384 * 2;
    float4* ea4 = (float4*)w;     w += (size_t)SCAP * 16;
    int* srcs = (int*)w;          w += (size_t)SCAP * 4;
    // zero-region: deg, cursor, red contiguous -> ONE memset
    int* deg = (int*)w;           w += (size_t)N * 4;
    int* cursor = (int*)w;        w += (size_t)N * 4;
    float* red = (float*)w;       w += (size_t)RSLOTS * 2 * 4;
    float* scal = (float*)w;      w += 16;
    int* slotbase = (int*)w;      w += (size_t)N * 4;
    int* g4 = (int*)w;            w += (size_t)G * 4;
    int* groupstart = (int*)w;    w += (size_t)(G + 1) * 4;
    int* gcur = (int*)w;          w += (size_t)G * 4;

    // ---- build + prep
    hipMemsetAsync(deg, 0, (size_t)(2 * N + 2 * RSLOTS) * 4, stream);
    k_count<<<(E + 255) / 256, 256, 0, stream>>>(dst, deg, E);
    k_group<<<(G + 255) / 256, 256, 0, stream>>>(deg, g4, G, N);
    k_scan<<<1, 1024, 0, stream>>>(g4, groupstart, gcur, G);
    k_nodebase<<<(N + 255) / 256, 256, 0, stream>>>(groupstart, slotbase, N);
    k_padinit<<<1024, 256, 0, stream>>>(srcs, ea4, groupstart, G);
    k_fill2<<<(E + 255) / 256, 256, 0, stream>>>(src, dst, eattr, cursor, slotbase, srcs, ea4, E);
    k_wprep<<<7, 256, 0, stream>>>(Wl, Wr, Wout, wz);
    k_cast<<<(N * HID / 4 + 255) / 256, 256, 0, stream>>>(x, hb, N * HID);

    int gb = (N + 127) / 128;
    for (int l = 0; l < NLAYER; l++) {
        k_gemm_mfma<true><<<dim3(gb, 2), 256, 0, stream>>>(
            hb, wz + (size_t)(2 * l) * 16384, wz + (size_t)(2 * l + 1) * 16384,
            xlb, xrb, nullptr, N);
        k_aggregate<<<(G + 3) / 4, 256, 0, stream>>>(
            xlb, xrb, srcs, ea4, groupstart,
            We + (size_t)l * EDIM * HID, att + (size_t)l * NHEAD * CH, tmpp, red, N, G);
        k_finish<<<1, 256, 0, stream>>>(red, scal, (float)N * (float)HID);
        k_ln_gelu<<<((N * HID / 8) + 255) / 256, 256, 0, stream>>>(
            (const uint4*)tmpp, lnw + (size_t)l * HID, lnb + (size_t)l * HID, scal,
            (uint4*)hb, N * HID / 8);
    }
    k_gemm_mfma<false><<<dim3(gb, 1), 256, 0, stream>>>(
        hb, wz + (size_t)6 * 16384, wz + (size_t)6 * 16384, out, out, bout, N);
}

// Round 2
// 490.761 us; speedup vs baseline: 1.0813x; 1.0813x over previous
//
#include <hip/hip_runtime.h>
#include <hip/hip_bf16.h>
#include <math.h>

#define HID 128
#define NHEAD 4
#define CH 32
#define NLAYER 3
#define EDIM 3
#define EPSLN 1e-5f
#define SLOPE 0.2f
#define RSLOTS 4096   // LN-reduction slots (pairs); 32 KB
#define PAD_W -1e30f  // additive sentinel: exp(part + PAD_W) == 0

typedef __bf16 bf16x8 __attribute__((ext_vector_type(8)));
typedef float f32x4 __attribute__((ext_vector_type(4)));

__device__ __forceinline__ float bflo(unsigned d) { return __uint_as_float(d << 16); }
__device__ __forceinline__ float bfhi(unsigned d) { return __uint_as_float(d & 0xffff0000u); }

// ---------------------------------------------------------------- degree count
__global__ void k_count(const int* __restrict__ dst, int* __restrict__ deg, int E) {
    int i = blockIdx.x * blockDim.x + threadIdx.x;
    if (i < E) atomicAdd(&deg[dst[i]], 1);
}

// ---------------------------------------------------------------- single-block scan
// Scans per-group totals where group value = sum_{j<4} pad4(deg[4g+j]).
__global__ __launch_bounds__(1024) void k_scan(const int* __restrict__ deg,
                                               int* __restrict__ outs,
                                               int N, int G) {
    __shared__ int sw[16];
    __shared__ int scarry;
    int tid = threadIdx.x, lane = tid & 63, wid = tid >> 6;
    if (tid == 0) scarry = 0;
    __syncthreads();
    for (int base = 0; base < G; base += 1024) {
        int i = base + tid;
        int v = 0;
        if (i < G) {
#pragma unroll
            for (int j = 0; j < 4; j++) {
                int n = 4 * i + j;
                if (n < N) v += (deg[n] + 3) & ~3;
            }
        }
        int x = v;
#pragma unroll
        for (int o = 1; o < 64; o <<= 1) { int y = __shfl_up(x, o, 64); if (lane >= o) x += y; }
        if (lane == 63) sw[wid] = x;
        __syncthreads();
        int carry = scarry;
        if (tid < 16) {
            int s = sw[tid];
#pragma unroll
            for (int o = 1; o < 16; o <<= 1) { int y = __shfl_up(s, o, 64); if (tid >= o) s += y; }
            sw[tid] = s;
        }
        __syncthreads();
        int wofs = (wid == 0) ? 0 : sw[wid - 1];
        int incl = carry + wofs + x;
        if (i < G) outs[i] = incl - v;
        __syncthreads();
        if (tid == 0) scarry = carry + sw[15];
        __syncthreads();
    }
    if (tid == 0) outs[G] = scarry;
}

// ---------------------------------------------------------------- per-node base + pad init
// slotbase[i] = groupstart[i>>2] + sum of pad4(deg) of earlier nodes in group.
// Also initializes ONLY the pad slots (deg..pad4-1) of each node.
__global__ void k_nodepad(const int* __restrict__ deg, const int* __restrict__ groupstart,
                          int* __restrict__ slotbase, int* __restrict__ srcs,
                          float4* __restrict__ ea4, int N) {
    int i = blockIdx.x * blockDim.x + threadIdx.x;
    if (i >= N) return;
    int g = i >> 2;
    int base = groupstart[g];
    int i0 = g * 4;
#pragma unroll
    for (int j = 0; j < 3; j++)
        if (i0 + j < i) base += (deg[i0 + j] + 3) & ~3;
    slotbase[i] = base;
    int d = deg[i];
    int pd = (d + 3) & ~3;
    for (int j = d; j < pd; j++) {
        srcs[base + j] = 0;
        ea4[base + j] = make_float4(0.f, 0.f, 0.f, PAD_W);
    }
}

__global__ void k_fill2(const int* __restrict__ src, const int* __restrict__ dst,
                        const float* __restrict__ eattr, int* __restrict__ cursor,
                        const int* __restrict__ slotbase, int* __restrict__ srcs,
                        float4* __restrict__ ea4, int E) {
    int i = blockIdx.x * blockDim.x + threadIdx.x;
    if (i < E) {
        int n = dst[i];
        int pos = atomicAdd(&cursor[n], 1);
        int slot = slotbase[n] + pos;
        srcs[slot] = src[i];
        ea4[slot] = make_float4(eattr[3 * i], eattr[3 * i + 1], eattr[3 * i + 2], 0.f);
    }
}

// ---------------------------------------------------------------- weight prep
// bf16 + MFMA B-fragment swizzle: wz[((s*8+n)*64+q)*8+j] = W[(s*32+(q>>4)*8+j)*128 + n*16+(q&15)]
__global__ __launch_bounds__(256) void k_wprep(const float* __restrict__ Wl,
                                               const float* __restrict__ Wr,
                                               const float* __restrict__ Wout,
                                               __hip_bfloat16* __restrict__ wz) {
    int b = blockIdx.x;  // 0..6: l0Wl,l0Wr,l1Wl,l1Wr,l2Wl,l2Wr,Wout
    const float* src = (b < 6) ? ((b & 1) ? Wr + (size_t)(b >> 1) * 16384
                                          : Wl + (size_t)(b >> 1) * 16384)
                               : Wout;
    for (int t = threadIdx.x; t < 16384; t += 256) {
        int j = t & 7, q = (t >> 3) & 63, n = (t >> 9) & 7, s = t >> 12;
        int k = s * 32 + (q >> 4) * 8 + j;
        int c = n * 16 + (q & 15);
        wz[(size_t)b * 16384 + t] = __float2bfloat16(src[k * 128 + c]);
    }
}

__global__ __launch_bounds__(256) void k_cast(const float* __restrict__ in,
                                              __hip_bfloat16* __restrict__ out, int n) {
    int i = (blockIdx.x * 256 + threadIdx.x) * 4;
    if (i < n) {
        float4 v = *(const float4*)&in[i];
        __hip_bfloat16 o[4] = {__float2bfloat16(v.x), __float2bfloat16(v.y),
                               __float2bfloat16(v.z), __float2bfloat16(v.w)};
        *(ushort4*)&out[i] = *(ushort4*)o;
    }
}

// ---------------------------------------------------------------- MFMA GEMM
// Y = Xb(bf16) @ W(bf16 pre-swizzled); out bf16 (layers) or fp32+bias (final).
template <bool BF16OUT>
__global__ __launch_bounds__(256) void k_gemm_mfma(const __hip_bfloat16* __restrict__ Xb,
                                                   const __hip_bfloat16* __restrict__ Wz0,
                                                   const __hip_bfloat16* __restrict__ Wz1,
                                                   void* __restrict__ Y0v,
                                                   void* __restrict__ Y1v,
                                                   const float* __restrict__ bias, int N) {
    __shared__ __hip_bfloat16 sW[16384];  // 32 KB
    const __hip_bfloat16* Wz = blockIdx.y ? Wz1 : Wz0;
    void* Yv = blockIdx.y ? Y1v : Y0v;
    int tid = threadIdx.x;
    {
        const float4* s4 = (const float4*)Wz;
        float4* d4 = (float4*)sW;
#pragma unroll
        for (int i = 0; i < 8; i++) d4[tid + 256 * i] = s4[tid + 256 * i];
    }
    __syncthreads();

    int wv = tid >> 6, lane = tid & 63;
    int quad = lane >> 4, l16 = lane & 15;
    int mbase = blockIdx.x * 128 + wv * 32;

    f32x4 acc[2][8];
#pragma unroll
    for (int mt = 0; mt < 2; mt++)
#pragma unroll
        for (int n = 0; n < 8; n++) acc[mt][n] = (f32x4){0.f, 0.f, 0.f, 0.f};

#pragma unroll
    for (int s = 0; s < 4; s++) {
        bf16x8 a[2];
#pragma unroll
        for (int mt = 0; mt < 2; mt++) {
            int row = mbase + mt * 16 + l16;
            row = (row < N) ? row : (N - 1);
            a[mt] = *(const bf16x8*)&Xb[(size_t)row * HID + s * 32 + quad * 8];
        }
#pragma unroll
        for (int n = 0; n < 8; n++) {
            bf16x8 b = *(const bf16x8*)&sW[((s * 8 + n) * 64 + lane) * 8];
            acc[0][n] = __builtin_amdgcn_mfma_f32_16x16x32_bf16(a[0], b, acc[0][n], 0, 0, 0);
            acc[1][n] = __builtin_amdgcn_mfma_f32_16x16x32_bf16(a[1], b, acc[1][n], 0, 0, 0);
        }
    }

    float bv[8];
#pragma unroll
    for (int n = 0; n < 8; n++) bv[n] = bias ? bias[n * 16 + l16] : 0.f;

#pragma unroll
    for (int mt = 0; mt < 2; mt++)
#pragma unroll
        for (int reg = 0; reg < 4; reg++) {
            int row = mbase + mt * 16 + quad * 4 + reg;
            if (row < N) {
                if (BF16OUT) {
                    __hip_bfloat16* yp = (__hip_bfloat16*)Yv + (size_t)row * HID + l16;
#pragma unroll
                    for (int n = 0; n < 8; n++) yp[n * 16] = __float2bfloat16(acc[mt][n][reg]);
                } else {
                    float* yp = (float*)Yv + (size_t)row * HID + l16;
#pragma unroll
                    for (int n = 0; n < 8; n++) yp[n * 16] = acc[mt][n][reg] + bv[n];
                }
            }
        }
}

// ---------------------------------------------------------------- GATv2 aggregate (per-node)
// One wave per node: steps = ceil(deg/4), 4 edges of the SAME node per step.
// bf16 xl/xr (exact unpack via shifts), fp32 math, packed-bf16 tmp out.
__global__ __launch_bounds__(256) void k_aggregate(const __hip_bfloat16* __restrict__ xlb,
                                                   const __hip_bfloat16* __restrict__ xrb,
                                                   const int* __restrict__ srcs,
                                                   const float4* __restrict__ ea4,
                                                   const int* __restrict__ deg,
                                                   const int* __restrict__ slotbase,
                                                   const float* __restrict__ We,
                                                   const float* __restrict__ att,
                                                   unsigned* __restrict__ tmpp,
                                                   float* __restrict__ red, int N) {
    int wid = threadIdx.x >> 6;
    int lane = threadIdx.x & 63;
    int node = blockIdx.x * 4 + wid;
    if (node >= N) return;
    int c0 = lane * 2;
    int head = lane >> 4;

    float we00 = We[c0], we01 = We[c0 + 1];
    float we10 = We[HID + c0], we11 = We[HID + c0 + 1];
    float we20 = We[2 * HID + c0], we21 = We[2 * HID + c0 + 1];
    float at0 = att[head * CH + (c0 & 31)];
    float at1 = att[head * CH + (c0 & 31) + 1];

    int base = __builtin_amdgcn_readfirstlane(slotbase[node]);
    int steps = __builtin_amdgcn_readfirstlane((deg[node] + 3) >> 2);

    unsigned dxr = *(const unsigned*)&xrb[(size_t)node * HID + c0];
    float xr0 = bflo(dxr), xr1 = bfhi(dxr);

    float l = 0.f, A0 = 0.f, A1 = 0.f;

    const int4* sp = (const int4*)(srcs + base);
    const float4* ep = ea4 + base;

    for (int t = 0; t < steps; t++) {
        int4 s4 = sp[t];
        int s[4] = {s4.x, s4.y, s4.z, s4.w};
        float4 ev[4];
#pragma unroll
        for (int j = 0; j < 4; j++) ev[j] = ep[4 * t + j];
        unsigned dv[4];
#pragma unroll
        for (int j = 0; j < 4; j++)
            dv[j] = *(const unsigned*)&xlb[(size_t)s[j] * HID + c0];  // 4 indep gathers, 4B each
#pragma unroll
        for (int j = 0; j < 4; j++) {
            float xv0 = bflo(dv[j]), xv1 = bfhi(dv[j]);
            float m0 = xv0 + xr0 + fmaf(ev[j].x, we00, fmaf(ev[j].y, we10, ev[j].z * we20));
            float m1 = xv1 + xr1 + fmaf(ev[j].x, we01, fmaf(ev[j].y, we11, ev[j].z * we21));
            m0 = (m0 > 0.f) ? m0 : SLOPE * m0;
            m1 = (m1 > 0.f) ? m1 : SLOPE * m1;
            float part = fmaf(m0, at0, m1 * at1);
            part += __shfl_xor(part, 1);
            part += __shfl_xor(part, 2);
            part += __shfl_xor(part, 4);
            part += __shfl_xor(part, 8);
            float p = __expf(part + ev[j].w);  // padding: exp(-1e30)=0
            l += p;
            A0 = fmaf(p, xv0, A0);
            A1 = fmaf(p, xv1, A1);
        }
    }

    float inv = 1.f / (l + 1e-16f);
    float o0 = A0 * inv, o1 = A1 * inv;
    __hip_bfloat16 pk[2] = {__float2bfloat16(o0), __float2bfloat16(o1)};
    tmpp[(size_t)node * (HID / 2) + lane] = *(unsigned*)pk;

    float ssum = o0 + o1;                 // LN stats from pre-rounded fp32
    float ssq = fmaf(o0, o0, o1 * o1);
#pragma unroll
    for (int o = 32; o >= 1; o >>= 1) { ssum += __shfl_xor(ssum, o); ssq += __shfl_xor(ssq, o); }
    if (lane == 0) {
        int slot = (node & (RSLOTS - 1)) * 2;
        atomicAdd(&red[slot], ssum);
        atomicAdd(&red[slot + 1], ssq);
    }
}

// ---------------------------------------------------------------- LN finish (also re-zeros red)
__global__ __launch_bounds__(256) void k_finish(float* __restrict__ red,
                                                float* __restrict__ scal, float M) {
    __shared__ float ls[8];
    int tid = threadIdx.x;
    float s = 0.f, q = 0.f;
    for (int i = tid; i < RSLOTS; i += 256) { s += red[2 * i]; q += red[2 * i + 1]; }
#pragma unroll
    for (int o = 32; o >= 1; o >>= 1) { s += __shfl_xor(s, o); q += __shfl_xor(q, o); }
    if ((tid & 63) == 0) { ls[(tid >> 6) * 2] = s; ls[(tid >> 6) * 2 + 1] = q; }
    __syncthreads();
    if (tid == 0) {
        float S = ls[0] + ls[2] + ls[4] + ls[6];
        float Q = ls[1] + ls[3] + ls[5] + ls[7];
        float mean = S / M;
        float var = Q / M - mean * mean;
        scal[0] = mean;
        scal[1] = rsqrtf(var + EPSLN);
    }
    // re-zero for the next layer (next aggregate sees zeros via kernel boundary)
    for (int i = tid; i < RSLOTS * 2; i += 256) red[i] = 0.f;
}

// ---------------------------------------------------------------- LN + gelu (bf16 in/out)
__global__ __launch_bounds__(256) void k_ln_gelu(const uint4* __restrict__ in4,
                                                 const float* __restrict__ w,
                                                 const float* __restrict__ b,
                                                 const float* __restrict__ scal,
                                                 uint4* __restrict__ out4, int n8) {
    int i = blockIdx.x * blockDim.x + threadIdx.x;
    if (i >= n8) return;
    float mean = scal[0], inv = scal[1];
    uint4 v = in4[i];
    int col = (i * 8) & 127;
    float4 w0 = *(const float4*)&w[col], w1 = *(const float4*)&w[col + 4];
    float4 b0 = *(const float4*)&b[col], b1 = *(const float4*)&b[col + 4];
    float r[8] = {bflo(v.x), bfhi(v.x), bflo(v.y), bfhi(v.y),
                  bflo(v.z), bfhi(v.z), bflo(v.w), bfhi(v.w)};
    float wr[8] = {w0.x, w0.y, w0.z, w0.w, w1.x, w1.y, w1.z, w1.w};
    float br[8] = {b0.x, b0.y, b0.z, b0.w, b1.x, b1.y, b1.z, b1.w};
    __hip_bfloat16 o[8];
#pragma unroll
    for (int j = 0; j < 8; j++) {
        float t = fmaf((r[j] - mean) * inv, wr[j], br[j]);
        o[j] = __float2bfloat16(0.5f * t * (1.f + erff(t * 0.70710678118654752f)));
    }
    out4[i] = *(uint4*)o;
}

// ---------------------------------------------------------------- launch
extern "C" void kernel_launch(void* const* d_in, const int* in_sizes, int n_in,
                              void* d_out, int out_size, void* d_ws, size_t ws_size,
                              hipStream_t stream) {
    const float* x = (const float*)d_in[0];
    const int* ei = (const int*)d_in[1];
    const float* eattr = (const float*)d_in[2];
    const float* Wl = (const float*)d_in[3];
    const float* Wr = (const float*)d_in[4];
    const float* We = (const float*)d_in[5];
    const float* att = (const float*)d_in[6];
    const float* lnw = (const float*)d_in[7];
    const float* lnb = (const float*)d_in[8];
    const float* Wout = (const float*)d_in[9];
    const float* bout = (const float*)d_in[10];
    float* out = (float*)d_out;

    int N = in_sizes[0] / HID;
    int E = in_sizes[1] / 2;
    int G = (N + 3) / 4;
    int SCAP = E + 8 * N;
    const int* src = ei;
    const int* dst = ei + E;

    char* w = (char*)d_ws;
    __hip_bfloat16* hb = (__hip_bfloat16*)w;   w += (size_t)N * HID * 2;
    __hip_bfloat16* xlb = (__hip_bfloat16*)w;  w += (size_t)N * HID * 2;
    __hip_bfloat16* xrb = (__hip_bfloat16*)w;  w += (size_t)N * HID * 2;
    unsigned* tmpp = (unsigned*)w;             w += (size_t)N * HID * 2;
    __hip_bfloat16* wz = (__hip_bfloat16*)w;   w += (size_t)7 * 16384 * 2;
    float4* ea4 = (float4*)w;     w += (size_t)SCAP * 16;
    int* srcs = (int*)w;          w += (size_t)SCAP * 4;
    // zero-region: deg, cursor, red contiguous -> ONE memset
    int* deg = (int*)w;           w += (size_t)N * 4;
    int* cursor = (int*)w;        w += (size_t)N * 4;
    float* red = (float*)w;       w += (size_t)RSLOTS * 2 * 4;
    float* scal = (float*)w;      w += 16;
    int* slotbase = (int*)w;      w += (size_t)N * 4;
    int* groupstart = (int*)w;    w += (size_t)(G + 1) * 4;

    // ---- build + prep
    hipMemsetAsync(deg, 0, (size_t)(2 * N + 2 * RSLOTS) * 4, stream);
    k_count<<<(E + 255) / 256, 256, 0, stream>>>(dst, deg, E);
    k_scan<<<1, 1024, 0, stream>>>(deg, groupstart, N, G);
    k_nodepad<<<(N + 255) / 256, 256, 0, stream>>>(deg, groupstart, slotbase, srcs, ea4, N);
    k_fill2<<<(E + 255) / 256, 256, 0, stream>>>(src, dst, eattr, cursor, slotbase, srcs, ea4, E);
    k_wprep<<<7, 256, 0, stream>>>(Wl, Wr, Wout, wz);
    k_cast<<<(N * HID / 4 + 255) / 256, 256, 0, stream>>>(x, hb, N * HID);

    int gb = (N + 127) / 128;
    for (int l = 0; l < NLAYER; l++) {
        k_gemm_mfma<true><<<dim3(gb, 2), 256, 0, stream>>>(
            hb, wz + (size_t)(2 * l) * 16384, wz + (size_t)(2 * l + 1) * 16384,
            xlb, xrb, nullptr, N);
        k_aggregate<<<(N + 3) / 4, 256, 0, stream>>>(
            xlb, xrb, srcs, ea4, deg, slotbase,
            We + (size_t)l * EDIM * HID, att + (size_t)l * NHEAD * CH, tmpp, red, N);
        k_finish<<<1, 256, 0, stream>>>(red, scal, (float)N * (float)HID);
        k_ln_gelu<<<((N * HID / 8) + 255) / 256, 256, 0, stream>>>(
            (const uint4*)tmpp, lnw + (size_t)l * HID, lnb + (size_t)l * HID, scal,
            (uint4*)hb, N * HID / 8);
    }
    k_gemm_mfma<false><<<dim3(gb, 1), 256, 0, stream>>>(
        hb, wz + (size_t)6 * 16384, wz + (size_t)6 * 16384, out, out, bout, N);
}

// Round 3
// 466.668 us; speedup vs baseline: 1.1372x; 1.0516x over previous
//
#include <hip/hip_runtime.h>
#include <hip/hip_bf16.h>
#include <math.h>

#define HID 128
#define NHEAD 4
#define CH 32
#define NLAYER 3
#define EDIM 3
#define EPSLN 1e-5f
#define SLOPE 0.2f
#define RSLOTS 4096   // LN-reduction slots (pairs); 32 KB
#define PAD_W -1e30f  // additive sentinel: exp(part + PAD_W) == 0

typedef __bf16 bf16x8 __attribute__((ext_vector_type(8)));
typedef float f32x4 __attribute__((ext_vector_type(4)));

__device__ __forceinline__ float bflo(unsigned d) { return __uint_as_float(d << 16); }
__device__ __forceinline__ float bfhi(unsigned d) { return __uint_as_float(d & 0xffff0000u); }

// ---------------------------------------------------------------- degree count
__global__ void k_count(const int* __restrict__ dst, int* __restrict__ deg, int E) {
    int i = blockIdx.x * blockDim.x + threadIdx.x;
    if (i < E) atomicAdd(&deg[dst[i]], 1);
}

// ---------------------------------------------------------------- single-block scan
// Scans per-group totals where group value = sum_{j<4} pad4(deg[4g+j]).
__global__ __launch_bounds__(1024) void k_scan(const int* __restrict__ deg,
                                               int* __restrict__ outs,
                                               int N, int G) {
    __shared__ int sw[16];
    __shared__ int scarry;
    int tid = threadIdx.x, lane = tid & 63, wid = tid >> 6;
    if (tid == 0) scarry = 0;
    __syncthreads();
    for (int base = 0; base < G; base += 1024) {
        int i = base + tid;
        int v = 0;
        if (i < G) {
            int n0 = 4 * i;
            if (n0 + 3 < N) {
                int4 d4 = *(const int4*)&deg[n0];
                v = ((d4.x + 3) & ~3) + ((d4.y + 3) & ~3) +
                    ((d4.z + 3) & ~3) + ((d4.w + 3) & ~3);
            } else {
#pragma unroll
                for (int j = 0; j < 4; j++) {
                    int n = n0 + j;
                    if (n < N) v += (deg[n] + 3) & ~3;
                }
            }
        }
        int x = v;
#pragma unroll
        for (int o = 1; o < 64; o <<= 1) { int y = __shfl_up(x, o, 64); if (lane >= o) x += y; }
        if (lane == 63) sw[wid] = x;
        __syncthreads();
        int carry = scarry;
        if (tid < 16) {
            int s = sw[tid];
#pragma unroll
            for (int o = 1; o < 16; o <<= 1) { int y = __shfl_up(s, o, 64); if (tid >= o) s += y; }
            sw[tid] = s;
        }
        __syncthreads();
        int wofs = (wid == 0) ? 0 : sw[wid - 1];
        int incl = carry + wofs + x;
        if (i < G) outs[i] = incl - v;
        __syncthreads();
        if (tid == 0) scarry = carry + sw[15];
        __syncthreads();
    }
    if (tid == 0) outs[G] = scarry;
}

// ---------------------------------------------------------------- per-node base + pad init
// slotbase[i]=cursor[i]= groupstart[i>>2] + earlier nodes' pad4(deg) in group.
// Initializes ONLY the pad slots (deg..pad4-1): {src=-1, e=0}.
__global__ void k_nodepad(const int* __restrict__ deg, const int* __restrict__ groupstart,
                          int* __restrict__ slotbase, int* __restrict__ cursor,
                          int4* __restrict__ slots, int N) {
    int i = blockIdx.x * blockDim.x + threadIdx.x;
    if (i >= N) return;
    int g = i >> 2;
    int base = groupstart[g];
    int i0 = g * 4;
#pragma unroll
    for (int j = 0; j < 3; j++)
        if (i0 + j < i) base += (deg[i0 + j] + 3) & ~3;
    slotbase[i] = base;
    cursor[i] = base;
    int d = deg[i];
    int pd = (d + 3) & ~3;
    for (int j = d; j < pd; j++) slots[base + j] = make_int4(-1, 0, 0, 0);
}

// one 16B scattered store per edge: {src, e0, e1, e2}
__global__ void k_fill2(const int* __restrict__ src, const int* __restrict__ dst,
                        const float* __restrict__ eattr, int* __restrict__ cursor,
                        int4* __restrict__ slots, int E) {
    int i = blockIdx.x * blockDim.x + threadIdx.x;
    if (i < E) {
        int n = dst[i];
        int slot = atomicAdd(&cursor[n], 1);
        slots[slot] = make_int4(src[i], __float_as_int(eattr[3 * i]),
                                __float_as_int(eattr[3 * i + 1]),
                                __float_as_int(eattr[3 * i + 2]));
    }
}

// ---------------------------------------------------------------- weight prep
// bf16 + MFMA B-fragment swizzle: wz[((s*8+n)*64+q)*8+j] = W[(s*32+(q>>4)*8+j)*128 + n*16+(q&15)]
__global__ __launch_bounds__(256) void k_wprep(const float* __restrict__ Wl,
                                               const float* __restrict__ Wr,
                                               const float* __restrict__ Wout,
                                               __hip_bfloat16* __restrict__ wz) {
    int b = blockIdx.x;  // 0..6: l0Wl,l0Wr,l1Wl,l1Wr,l2Wl,l2Wr,Wout
    const float* src = (b < 6) ? ((b & 1) ? Wr + (size_t)(b >> 1) * 16384
                                          : Wl + (size_t)(b >> 1) * 16384)
                               : Wout;
    for (int t = threadIdx.x; t < 16384; t += 256) {
        int j = t & 7, q = (t >> 3) & 63, n = (t >> 9) & 7, s = t >> 12;
        int k = s * 32 + (q >> 4) * 8 + j;
        int c = n * 16 + (q & 15);
        wz[(size_t)b * 16384 + t] = __float2bfloat16(src[k * 128 + c]);
    }
}

__global__ __launch_bounds__(256) void k_cast(const float* __restrict__ in,
                                              __hip_bfloat16* __restrict__ out, int n) {
    int i = (blockIdx.x * 256 + threadIdx.x) * 4;
    if (i < n) {
        float4 v = *(const float4*)&in[i];
        __hip_bfloat16 o[4] = {__float2bfloat16(v.x), __float2bfloat16(v.y),
                               __float2bfloat16(v.z), __float2bfloat16(v.w)};
        *(ushort4*)&out[i] = *(ushort4*)o;
    }
}

// ---------------------------------------------------------------- MFMA GEMM
// Y = Xb(bf16) @ W(bf16 pre-swizzled); out bf16 (layers) or fp32+bias (final).
template <bool BF16OUT>
__global__ __launch_bounds__(256) void k_gemm_mfma(const __hip_bfloat16* __restrict__ Xb,
                                                   const __hip_bfloat16* __restrict__ Wz0,
                                                   const __hip_bfloat16* __restrict__ Wz1,
                                                   void* __restrict__ Y0v,
                                                   void* __restrict__ Y1v,
                                                   const float* __restrict__ bias, int N) {
    __shared__ __hip_bfloat16 sW[16384];  // 32 KB
    const __hip_bfloat16* Wz = blockIdx.y ? Wz1 : Wz0;
    void* Yv = blockIdx.y ? Y1v : Y0v;
    int tid = threadIdx.x;
    {
        const float4* s4 = (const float4*)Wz;
        float4* d4 = (float4*)sW;
#pragma unroll
        for (int i = 0; i < 8; i++) d4[tid + 256 * i] = s4[tid + 256 * i];
    }
    __syncthreads();

    int wv = tid >> 6, lane = tid & 63;
    int quad = lane >> 4, l16 = lane & 15;
    int mbase = blockIdx.x * 128 + wv * 32;

    f32x4 acc[2][8];
#pragma unroll
    for (int mt = 0; mt < 2; mt++)
#pragma unroll
        for (int n = 0; n < 8; n++) acc[mt][n] = (f32x4){0.f, 0.f, 0.f, 0.f};

#pragma unroll
    for (int s = 0; s < 4; s++) {
        bf16x8 a[2];
#pragma unroll
        for (int mt = 0; mt < 2; mt++) {
            int row = mbase + mt * 16 + l16;
            row = (row < N) ? row : (N - 1);
            a[mt] = *(const bf16x8*)&Xb[(size_t)row * HID + s * 32 + quad * 8];
        }
#pragma unroll
        for (int n = 0; n < 8; n++) {
            bf16x8 b = *(const bf16x8*)&sW[((s * 8 + n) * 64 + lane) * 8];
            acc[0][n] = __builtin_amdgcn_mfma_f32_16x16x32_bf16(a[0], b, acc[0][n], 0, 0, 0);
            acc[1][n] = __builtin_amdgcn_mfma_f32_16x16x32_bf16(a[1], b, acc[1][n], 0, 0, 0);
        }
    }

    float bv[8];
#pragma unroll
    for (int n = 0; n < 8; n++) bv[n] = bias ? bias[n * 16 + l16] : 0.f;

#pragma unroll
    for (int mt = 0; mt < 2; mt++)
#pragma unroll
        for (int reg = 0; reg < 4; reg++) {
            int row = mbase + mt * 16 + quad * 4 + reg;
            if (row < N) {
                if (BF16OUT) {
                    __hip_bfloat16* yp = (__hip_bfloat16*)Yv + (size_t)row * HID + l16;
#pragma unroll
                    for (int n = 0; n < 8; n++) yp[n * 16] = __float2bfloat16(acc[mt][n][reg]);
                } else {
                    float* yp = (float*)Yv + (size_t)row * HID + l16;
#pragma unroll
                    for (int n = 0; n < 8; n++) yp[n * 16] = acc[mt][n][reg] + bv[n];
                }
            }
        }
}

// ---------------------------------------------------------------- GATv2 aggregate (per-node)
// One wave per node: steps = ceil(deg/4), 4 edges of the SAME node per step.
// Slot record: int4 {src(-1=pad), e0, e1, e2}.
__global__ __launch_bounds__(256) void k_aggregate(const __hip_bfloat16* __restrict__ xlb,
                                                   const __hip_bfloat16* __restrict__ xrb,
                                                   const int4* __restrict__ slots,
                                                   const int* __restrict__ deg,
                                                   const int* __restrict__ slotbase,
                                                   const float* __restrict__ We,
                                                   const float* __restrict__ att,
                                                   unsigned* __restrict__ tmpp,
                                                   float* __restrict__ red, int N) {
    int wid = threadIdx.x >> 6;
    int lane = threadIdx.x & 63;
    int node = blockIdx.x * 4 + wid;
    if (node >= N) return;
    int c0 = lane * 2;
    int head = lane >> 4;

    float we00 = We[c0], we01 = We[c0 + 1];
    float we10 = We[HID + c0], we11 = We[HID + c0 + 1];
    float we20 = We[2 * HID + c0], we21 = We[2 * HID + c0 + 1];
    float at0 = att[head * CH + (c0 & 31)];
    float at1 = att[head * CH + (c0 & 31) + 1];

    int base = __builtin_amdgcn_readfirstlane(slotbase[node]);
    int steps = __builtin_amdgcn_readfirstlane((deg[node] + 3) >> 2);

    unsigned dxr = *(const unsigned*)&xrb[(size_t)node * HID + c0];
    float xr0 = bflo(dxr), xr1 = bfhi(dxr);

    float l = 0.f, A0 = 0.f, A1 = 0.f;

    const int4* vp = slots + base;

    for (int t = 0; t < steps; t++) {
        int4 v[4];
#pragma unroll
        for (int j = 0; j < 4; j++) v[j] = vp[4 * t + j];
        unsigned dv[4];
#pragma unroll
        for (int j = 0; j < 4; j++) {
            int si = max(v[j].x, 0);
            dv[j] = *(const unsigned*)&xlb[(size_t)si * HID + c0];  // 4 indep gathers, 4B each
        }
#pragma unroll
        for (int j = 0; j < 4; j++) {
            float e0 = __int_as_float(v[j].y);
            float e1 = __int_as_float(v[j].z);
            float e2 = __int_as_float(v[j].w);
            float padw = (v[j].x < 0) ? PAD_W : 0.f;
            float xv0 = bflo(dv[j]), xv1 = bfhi(dv[j]);
            float m0 = xv0 + xr0 + fmaf(e0, we00, fmaf(e1, we10, e2 * we20));
            float m1 = xv1 + xr1 + fmaf(e0, we01, fmaf(e1, we11, e2 * we21));
            m0 = (m0 > 0.f) ? m0 : SLOPE * m0;
            m1 = (m1 > 0.f) ? m1 : SLOPE * m1;
            float part = fmaf(m0, at0, m1 * at1);
            part += __shfl_xor(part, 1);
            part += __shfl_xor(part, 2);
            part += __shfl_xor(part, 4);
            part += __shfl_xor(part, 8);
            float p = __expf(part + padw);  // padding: exp(-1e30)=0
            l += p;
            A0 = fmaf(p, xv0, A0);
            A1 = fmaf(p, xv1, A1);
        }
    }

    float inv = 1.f / (l + 1e-16f);
    float o0 = A0 * inv, o1 = A1 * inv;
    __hip_bfloat16 pk[2] = {__float2bfloat16(o0), __float2bfloat16(o1)};
    tmpp[(size_t)node * (HID / 2) + lane] = *(unsigned*)pk;

    float ssum = o0 + o1;                 // LN stats from pre-rounded fp32
    float ssq = fmaf(o0, o0, o1 * o1);
#pragma unroll
    for (int o = 32; o >= 1; o >>= 1) { ssum += __shfl_xor(ssum, o); ssq += __shfl_xor(ssq, o); }
    if (lane == 0) {
        int slot = (node & (RSLOTS - 1)) * 2;
        atomicAdd(&red[slot], ssum);
        atomicAdd(&red[slot + 1], ssq);
    }
}

// ---------------------------------------------------------------- LN finish (also re-zeros red)
__global__ __launch_bounds__(256) void k_finish(float* __restrict__ red,
                                                float* __restrict__ scal, float M) {
    __shared__ float ls[8];
    int tid = threadIdx.x;
    float s = 0.f, q = 0.f;
    for (int i = tid; i < RSLOTS; i += 256) { s += red[2 * i]; q += red[2 * i + 1]; }
#pragma unroll
    for (int o = 32; o >= 1; o >>= 1) { s += __shfl_xor(s, o); q += __shfl_xor(q, o); }
    if ((tid & 63) == 0) { ls[(tid >> 6) * 2] = s; ls[(tid >> 6) * 2 + 1] = q; }
    __syncthreads();
    if (tid == 0) {
        float S = ls[0] + ls[2] + ls[4] + ls[6];
        float Q = ls[1] + ls[3] + ls[5] + ls[7];
        float mean = S / M;
        float var = Q / M - mean * mean;
        scal[0] = mean;
        scal[1] = rsqrtf(var + EPSLN);
    }
    // re-zero for the next layer (next aggregate sees zeros via kernel boundary)
    for (int i = tid; i < RSLOTS * 2; i += 256) red[i] = 0.f;
}

// ---------------------------------------------------------------- LN + gelu (bf16 in/out)
__global__ __launch_bounds__(256) void k_ln_gelu(const uint4* __restrict__ in4,
                                                 const float* __restrict__ w,
                                                 const float* __restrict__ b,
                                                 const float* __restrict__ scal,
                                                 uint4* __restrict__ out4, int n8) {
    int i = blockIdx.x * blockDim.x + threadIdx.x;
    if (i >= n8) return;
    float mean = scal[0], inv = scal[1];
    uint4 v = in4[i];
    int col = (i * 8) & 127;
    float4 w0 = *(const float4*)&w[col], w1 = *(const float4*)&w[col + 4];
    float4 b0 = *(const float4*)&b[col], b1 = *(const float4*)&b[col + 4];
    float r[8] = {bflo(v.x), bfhi(v.x), bflo(v.y), bfhi(v.y),
                  bflo(v.z), bfhi(v.z), bflo(v.w), bfhi(v.w)};
    float wr[8] = {w0.x, w0.y, w0.z, w0.w, w1.x, w1.y, w1.z, w1.w};
    float br[8] = {b0.x, b0.y, b0.z, b0.w, b1.x, b1.y, b1.z, b1.w};
    __hip_bfloat16 o[8];
#pragma unroll
    for (int j = 0; j < 8; j++) {
        float t = fmaf((r[j] - mean) * inv, wr[j], br[j]);
        o[j] = __float2bfloat16(0.5f * t * (1.f + erff(t * 0.70710678118654752f)));
    }
    out4[i] = *(uint4*)o;
}

// ---------------------------------------------------------------- launch
extern "C" void kernel_launch(void* const* d_in, const int* in_sizes, int n_in,
                              void* d_out, int out_size, void* d_ws, size_t ws_size,
                              hipStream_t stream) {
    const float* x = (const float*)d_in[0];
    const int* ei = (const int*)d_in[1];
    const float* eattr = (const float*)d_in[2];
    const float* Wl = (const float*)d_in[3];
    const float* Wr = (const float*)d_in[4];
    const float* We = (const float*)d_in[5];
    const float* att = (const float*)d_in[6];
    const float* lnw = (const float*)d_in[7];
    const float* lnb = (const float*)d_in[8];
    const float* Wout = (const float*)d_in[9];
    const float* bout = (const float*)d_in[10];
    float* out = (float*)d_out;

    int N = in_sizes[0] / HID;
    int E = in_sizes[1] / 2;
    int G = (N + 3) / 4;
    int SCAP = E + 8 * N;
    const int* src = ei;
    const int* dst = ei + E;

    char* w = (char*)d_ws;
    __hip_bfloat16* hb = (__hip_bfloat16*)w;   w += (size_t)N * HID * 2;
    __hip_bfloat16* xlb = (__hip_bfloat16*)w;  w += (size_t)N * HID * 2;
    __hip_bfloat16* xrb = (__hip_bfloat16*)w;  w += (size_t)N * HID * 2;
    unsigned* tmpp = (unsigned*)w;             w += (size_t)N * HID * 2;
    __hip_bfloat16* wz = (__hip_bfloat16*)w;   w += (size_t)7 * 16384 * 2;
    int4* slots = (int4*)w;       w += (size_t)SCAP * 16;
    // zero-region: deg, cursor, red contiguous -> ONE memset
    int* deg = (int*)w;           w += (size_t)N * 4;
    int* cursor = (int*)w;        w += (size_t)N * 4;
    float* red = (float*)w;       w += (size_t)RSLOTS * 2 * 4;
    float* scal = (float*)w;      w += 16;
    int* slotbase = (int*)w;      w += (size_t)N * 4;
    int* groupstart = (int*)w;    w += (size_t)(G + 1) * 4;

    // ---- build + prep
    hipMemsetAsync(deg, 0, (size_t)(2 * N + 2 * RSLOTS) * 4, stream);
    k_count<<<(E + 255) / 256, 256, 0, stream>>>(dst, deg, E);
    k_scan<<<1, 1024, 0, stream>>>(deg, groupstart, N, G);
    k_nodepad<<<(N + 255) / 256, 256, 0, stream>>>(deg, groupstart, slotbase, cursor, slots, N);
    k_fill2<<<(E + 255) / 256, 256, 0, stream>>>(src, dst, eattr, cursor, slots, E);
    k_wprep<<<7, 256, 0, stream>>>(Wl, Wr, Wout, wz);
    k_cast<<<(N * HID / 4 + 255) / 256, 256, 0, stream>>>(x, hb, N * HID);

    int gb = (N + 127) / 128;
    for (int l = 0; l < NLAYER; l++) {
        k_gemm_mfma<true><<<dim3(gb, 2), 256, 0, stream>>>(
            hb, wz + (size_t)(2 * l) * 16384, wz + (size_t)(2 * l + 1) * 16384,
            xlb, xrb, nullptr, N);
        k_aggregate<<<(N + 3) / 4, 256, 0, stream>>>(
            xlb, xrb, slots, deg, slotbase,
            We + (size_t)l * EDIM * HID, att + (size_t)l * NHEAD * CH, tmpp, red, N);
        k_finish<<<1, 256, 0, stream>>>(red, scal, (float)N * (float)HID);
        k_ln_gelu<<<((N * HID / 8) + 255) / 256, 256, 0, stream>>>(
            (const uint4*)tmpp, lnw + (size_t)l * HID, lnb + (size_t)l * HID, scal,
            (uint4*)hb, N * HID / 8);
    }
    k_gemm_mfma<false><<<dim3(gb, 1), 256, 0, stream>>>(
        hb, wz + (size_t)6 * 16384, wz + (size_t)6 * 16384, out, out, bout, N);
}

// Round 4
// 453.957 us; speedup vs baseline: 1.1690x; 1.0280x over previous
//
#include <hip/hip_runtime.h>
#include <hip/hip_bf16.h>
#include <math.h>

#define HID 128
#define NHEAD 4
#define CH 32
#define NLAYER 3
#define EDIM 3
#define EPSLN 1e-5f
#define SLOPE 0.2f
#define RSLOTS 1024   // LN-reduction slots (pairs) per layer
#define PAD_W -1e30f  // additive sentinel: exp2(part + PAD_W) == 0
#define LOG2E 1.4426950408889634f

typedef __bf16 bf16x8 __attribute__((ext_vector_type(8)));
typedef float f32x4 __attribute__((ext_vector_type(4)));

__device__ __forceinline__ float bflo(unsigned d) { return __uint_as_float(d << 16); }
__device__ __forceinline__ float bfhi(unsigned d) { return __uint_as_float(d & 0xffff0000u); }

// ---------------------------------------------------------------- degree count
__global__ void k_count(const int* __restrict__ dst, int* __restrict__ deg, int E) {
    int i = blockIdx.x * blockDim.x + threadIdx.x;
    if (i < E) atomicAdd(&deg[dst[i]], 1);
}

// ---------------------------------------------------------------- single-block scan
// Scans per-group totals where group value = sum_{j<4} pad4(deg[4g+j]).
__global__ __launch_bounds__(1024) void k_scan(const int* __restrict__ deg,
                                               int* __restrict__ outs,
                                               int N, int G) {
    __shared__ int sw[16];
    __shared__ int scarry;
    int tid = threadIdx.x, lane = tid & 63, wid = tid >> 6;
    if (tid == 0) scarry = 0;
    __syncthreads();
    for (int base = 0; base < G; base += 1024) {
        int i = base + tid;
        int v = 0;
        if (i < G) {
            int n0 = 4 * i;
            if (n0 + 3 < N) {
                int4 d4 = *(const int4*)&deg[n0];
                v = ((d4.x + 3) & ~3) + ((d4.y + 3) & ~3) +
                    ((d4.z + 3) & ~3) + ((d4.w + 3) & ~3);
            } else {
#pragma unroll
                for (int j = 0; j < 4; j++) {
                    int n = n0 + j;
                    if (n < N) v += (deg[n] + 3) & ~3;
                }
            }
        }
        int x = v;
#pragma unroll
        for (int o = 1; o < 64; o <<= 1) { int y = __shfl_up(x, o, 64); if (lane >= o) x += y; }
        if (lane == 63) sw[wid] = x;
        __syncthreads();
        int carry = scarry;
        if (tid < 16) {
            int s = sw[tid];
#pragma unroll
            for (int o = 1; o < 16; o <<= 1) { int y = __shfl_up(s, o, 64); if (tid >= o) s += y; }
            sw[tid] = s;
        }
        __syncthreads();
        int wofs = (wid == 0) ? 0 : sw[wid - 1];
        int incl = carry + wofs + x;
        if (i < G) outs[i] = incl - v;
        __syncthreads();
        if (tid == 0) scarry = carry + sw[15];
        __syncthreads();
    }
    if (tid == 0) outs[G] = scarry;
}

// ---------------------------------------------------------------- per-node base + pad init
// slotbase[i]=cursor[i]= groupstart[i>>2] + earlier nodes' pad4(deg) in group.
// Initializes ONLY the pad slots (deg..pad4-1): {src=-1, e=0}.
__global__ void k_nodepad(const int* __restrict__ deg, const int* __restrict__ groupstart,
                          int* __restrict__ slotbase, int* __restrict__ cursor,
                          int4* __restrict__ slots, int N) {
    int i = blockIdx.x * blockDim.x + threadIdx.x;
    if (i >= N) return;
    int g = i >> 2;
    int base = groupstart[g];
    int i0 = g * 4;
#pragma unroll
    for (int j = 0; j < 3; j++)
        if (i0 + j < i) base += (deg[i0 + j] + 3) & ~3;
    slotbase[i] = base;
    cursor[i] = base;
    int d = deg[i];
    int pd = (d + 3) & ~3;
    for (int j = d; j < pd; j++) slots[base + j] = make_int4(-1, 0, 0, 0);
}

// one 16B scattered store per edge: {src, e0, e1, e2}
__global__ void k_fill2(const int* __restrict__ src, const int* __restrict__ dst,
                        const float* __restrict__ eattr, int* __restrict__ cursor,
                        int4* __restrict__ slots, int E) {
    int i = blockIdx.x * blockDim.x + threadIdx.x;
    if (i < E) {
        int n = dst[i];
        int slot = atomicAdd(&cursor[n], 1);
        slots[slot] = make_int4(src[i], __float_as_int(eattr[3 * i]),
                                __float_as_int(eattr[3 * i + 1]),
                                __float_as_int(eattr[3 * i + 2]));
    }
}

// ---------------------------------------------------------------- weight prep
// bf16 + MFMA B-fragment swizzle: wz[((s*8+n)*64+q)*8+j] = W[(s*32+(q>>4)*8+j)*128 + n*16+(q&15)]
__global__ __launch_bounds__(256) void k_wprep(const float* __restrict__ Wl,
                                               const float* __restrict__ Wr,
                                               const float* __restrict__ Wout,
                                               __hip_bfloat16* __restrict__ wz) {
    int b = blockIdx.x;  // 0..6: l0Wl,l0Wr,l1Wl,l1Wr,l2Wl,l2Wr,Wout
    const float* src = (b < 6) ? ((b & 1) ? Wr + (size_t)(b >> 1) * 16384
                                          : Wl + (size_t)(b >> 1) * 16384)
                               : Wout;
    for (int t = threadIdx.x; t < 16384; t += 256) {
        int j = t & 7, q = (t >> 3) & 63, n = (t >> 9) & 7, s = t >> 12;
        int k = s * 32 + (q >> 4) * 8 + j;
        int c = n * 16 + (q & 15);
        wz[(size_t)b * 16384 + t] = __float2bfloat16(src[k * 128 + c]);
    }
}

__global__ __launch_bounds__(256) void k_cast(const float* __restrict__ in,
                                              __hip_bfloat16* __restrict__ out, int n) {
    int i = (blockIdx.x * 256 + threadIdx.x) * 4;
    if (i < n) {
        float4 v = *(const float4*)&in[i];
        __hip_bfloat16 o[4] = {__float2bfloat16(v.x), __float2bfloat16(v.y),
                               __float2bfloat16(v.z), __float2bfloat16(v.w)};
        *(ushort4*)&out[i] = *(ushort4*)o;
    }
}

// ---------------------------------------------------------------- MFMA GEMM
// Y = Xb(bf16) @ W(bf16 pre-swizzled); out bf16 (layers) or fp32+bias (final).
template <bool BF16OUT>
__global__ __launch_bounds__(256) void k_gemm_mfma(const __hip_bfloat16* __restrict__ Xb,
                                                   const __hip_bfloat16* __restrict__ Wz0,
                                                   const __hip_bfloat16* __restrict__ Wz1,
                                                   void* __restrict__ Y0v,
                                                   void* __restrict__ Y1v,
                                                   const float* __restrict__ bias, int N) {
    __shared__ __hip_bfloat16 sW[16384];  // 32 KB
    const __hip_bfloat16* Wz = blockIdx.y ? Wz1 : Wz0;
    void* Yv = blockIdx.y ? Y1v : Y0v;
    int tid = threadIdx.x;
    {
        const float4* s4 = (const float4*)Wz;
        float4* d4 = (float4*)sW;
#pragma unroll
        for (int i = 0; i < 8; i++) d4[tid + 256 * i] = s4[tid + 256 * i];
    }
    __syncthreads();

    int wv = tid >> 6, lane = tid & 63;
    int quad = lane >> 4, l16 = lane & 15;
    int mbase = blockIdx.x * 128 + wv * 32;

    f32x4 acc[2][8];
#pragma unroll
    for (int mt = 0; mt < 2; mt++)
#pragma unroll
        for (int n = 0; n < 8; n++) acc[mt][n] = (f32x4){0.f, 0.f, 0.f, 0.f};

#pragma unroll
    for (int s = 0; s < 4; s++) {
        bf16x8 a[2];
#pragma unroll
        for (int mt = 0; mt < 2; mt++) {
            int row = mbase + mt * 16 + l16;
            row = (row < N) ? row : (N - 1);
            a[mt] = *(const bf16x8*)&Xb[(size_t)row * HID + s * 32 + quad * 8];
        }
#pragma unroll
        for (int n = 0; n < 8; n++) {
            bf16x8 b = *(const bf16x8*)&sW[((s * 8 + n) * 64 + lane) * 8];
            acc[0][n] = __builtin_amdgcn_mfma_f32_16x16x32_bf16(a[0], b, acc[0][n], 0, 0, 0);
            acc[1][n] = __builtin_amdgcn_mfma_f32_16x16x32_bf16(a[1], b, acc[1][n], 0, 0, 0);
        }
    }

    float bv[8];
#pragma unroll
    for (int n = 0; n < 8; n++) bv[n] = bias ? bias[n * 16 + l16] : 0.f;

#pragma unroll
    for (int mt = 0; mt < 2; mt++)
#pragma unroll
        for (int reg = 0; reg < 4; reg++) {
            int row = mbase + mt * 16 + quad * 4 + reg;
            if (row < N) {
                if (BF16OUT) {
                    __hip_bfloat16* yp = (__hip_bfloat16*)Yv + (size_t)row * HID + l16;
#pragma unroll
                    for (int n = 0; n < 8; n++) yp[n * 16] = __float2bfloat16(acc[mt][n][reg]);
                } else {
                    float* yp = (float*)Yv + (size_t)row * HID + l16;
#pragma unroll
                    for (int n = 0; n < 8; n++) yp[n * 16] = acc[mt][n][reg] + bv[n];
                }
            }
        }
}

// ---------------------------------------------------------------- GATv2 aggregate (per-node)
// One wave per node: steps = ceil(deg/4), 4 edges of the SAME node per step.
// Slot record: int4 {src(-1=pad), e0, e1, e2}. att pre-scaled by log2e -> v_exp direct.
__global__ __launch_bounds__(256) void k_aggregate(const __hip_bfloat16* __restrict__ xlb,
                                                   const __hip_bfloat16* __restrict__ xrb,
                                                   const int4* __restrict__ slots,
                                                   const int* __restrict__ deg,
                                                   const int* __restrict__ slotbase,
                                                   const float* __restrict__ We,
                                                   const float* __restrict__ att,
                                                   unsigned* __restrict__ tmpp,
                                                   float* __restrict__ red, int N) {
    int wid = threadIdx.x >> 6;
    int lane = threadIdx.x & 63;
    int node = blockIdx.x * 4 + wid;
    if (node >= N) return;
    int c0 = lane * 2;
    int head = lane >> 4;

    float we00 = We[c0], we01 = We[c0 + 1];
    float we10 = We[HID + c0], we11 = We[HID + c0 + 1];
    float we20 = We[2 * HID + c0], we21 = We[2 * HID + c0 + 1];
    float at0 = att[head * CH + (c0 & 31)] * LOG2E;        // fold log2e: exp2(m.at') == exp(m.at)
    float at1 = att[head * CH + (c0 & 31) + 1] * LOG2E;

    int base = __builtin_amdgcn_readfirstlane(slotbase[node]);
    int steps = __builtin_amdgcn_readfirstlane((deg[node] + 3) >> 2);

    unsigned dxr = *(const unsigned*)&xrb[(size_t)node * HID + c0];
    float xr0 = bflo(dxr), xr1 = bfhi(dxr);

    float l = 0.f, A0 = 0.f, A1 = 0.f;

    const int4* vp = slots + base;

    for (int t = 0; t < steps; t++) {
        int4 v[4];
#pragma unroll
        for (int j = 0; j < 4; j++) v[j] = vp[4 * t + j];
        unsigned dv[4];
#pragma unroll
        for (int j = 0; j < 4; j++) {
            int si = max(v[j].x, 0);
            dv[j] = *(const unsigned*)&xlb[(size_t)si * HID + c0];  // 4 indep gathers, 4B each
        }
#pragma unroll
        for (int j = 0; j < 4; j++) {
            float e0 = __int_as_float(v[j].y);
            float e1 = __int_as_float(v[j].z);
            float e2 = __int_as_float(v[j].w);
            float padw = (v[j].x < 0) ? PAD_W : 0.f;
            float xv0 = bflo(dv[j]), xv1 = bfhi(dv[j]);
            float m0 = xv0 + xr0 + fmaf(e0, we00, fmaf(e1, we10, e2 * we20));
            float m1 = xv1 + xr1 + fmaf(e0, we01, fmaf(e1, we11, e2 * we21));
            m0 = fmaxf(m0, SLOPE * m0);   // leakyrelu (slope<1): 2 ops, no cndmask
            m1 = fmaxf(m1, SLOPE * m1);
            float part = fmaf(m0, at0, m1 * at1);
            part += __shfl_xor(part, 1);
            part += __shfl_xor(part, 2);
            part += __shfl_xor(part, 4);
            part += __shfl_xor(part, 8);
            float p = __builtin_amdgcn_exp2f(part + padw);  // padding: exp2(-1e30)=0
            l += p;
            A0 = fmaf(p, xv0, A0);
            A1 = fmaf(p, xv1, A1);
        }
    }

    float inv = 1.f / (l + 1e-16f);
    float o0 = A0 * inv, o1 = A1 * inv;
    __hip_bfloat16 pk[2] = {__float2bfloat16(o0), __float2bfloat16(o1)};
    tmpp[(size_t)node * (HID / 2) + lane] = *(unsigned*)pk;

    float ssum = o0 + o1;                 // LN stats from pre-rounded fp32
    float ssq = fmaf(o0, o0, o1 * o1);
#pragma unroll
    for (int o = 32; o >= 1; o >>= 1) { ssum += __shfl_xor(ssum, o); ssq += __shfl_xor(ssq, o); }
    if (lane == 0) {
        int slot = (node & (RSLOTS - 1)) * 2;
        atomicAdd(&red[slot], ssum);
        atomicAdd(&red[slot + 1], ssq);
    }
}

// ---------------------------------------------------------------- LN + gelu (bf16 in/out)
// Each block redundantly reduces the layer's red[] (8 KB, L2-hot) -> no separate finish kernel.
__global__ __launch_bounds__(256) void k_ln_gelu(const uint4* __restrict__ in4,
                                                 const float* __restrict__ w,
                                                 const float* __restrict__ b,
                                                 const float* __restrict__ red,
                                                 float M,
                                                 uint4* __restrict__ out4, int n8) {
    __shared__ float ls[8];
    int tid = threadIdx.x;
    float s = 0.f, q = 0.f;
    const float2* r2 = (const float2*)red;
    for (int i = tid; i < RSLOTS; i += 256) { float2 rv = r2[i]; s += rv.x; q += rv.y; }
#pragma unroll
    for (int o = 32; o >= 1; o >>= 1) { s += __shfl_xor(s, o); q += __shfl_xor(q, o); }
    if ((tid & 63) == 0) { ls[(tid >> 6) * 2] = s; ls[(tid >> 6) * 2 + 1] = q; }
    __syncthreads();
    float S = ls[0] + ls[2] + ls[4] + ls[6];
    float Q = ls[1] + ls[3] + ls[5] + ls[7];
    float mean = S / M;
    float inv = rsqrtf(Q / M - mean * mean + EPSLN);

    int i = blockIdx.x * blockDim.x + tid;
    if (i >= n8) return;
    uint4 v = in4[i];
    int col = (i * 8) & 127;
    float4 w0 = *(const float4*)&w[col], w1 = *(const float4*)&w[col + 4];
    float4 b0 = *(const float4*)&b[col], b1 = *(const float4*)&b[col + 4];
    float r[8] = {bflo(v.x), bfhi(v.x), bflo(v.y), bfhi(v.y),
                  bflo(v.z), bfhi(v.z), bflo(v.w), bfhi(v.w)};
    float wr[8] = {w0.x, w0.y, w0.z, w0.w, w1.x, w1.y, w1.z, w1.w};
    float br[8] = {b0.x, b0.y, b0.z, b0.w, b1.x, b1.y, b1.z, b1.w};
    __hip_bfloat16 o[8];
#pragma unroll
    for (int j = 0; j < 8; j++) {
        float t = fmaf((r[j] - mean) * inv, wr[j], br[j]);
        o[j] = __float2bfloat16(0.5f * t * (1.f + erff(t * 0.70710678118654752f)));
    }
    out4[i] = *(uint4*)o;
}

// ---------------------------------------------------------------- launch
extern "C" void kernel_launch(void* const* d_in, const int* in_sizes, int n_in,
                              void* d_out, int out_size, void* d_ws, size_t ws_size,
                              hipStream_t stream) {
    const float* x = (const float*)d_in[0];
    const int* ei = (const int*)d_in[1];
    const float* eattr = (const float*)d_in[2];
    const float* Wl = (const float*)d_in[3];
    const float* Wr = (const float*)d_in[4];
    const float* We = (const float*)d_in[5];
    const float* att = (const float*)d_in[6];
    const float* lnw = (const float*)d_in[7];
    const float* lnb = (const float*)d_in[8];
    const float* Wout = (const float*)d_in[9];
    const float* bout = (const float*)d_in[10];
    float* out = (float*)d_out;

    int N = in_sizes[0] / HID;
    int E = in_sizes[1] / 2;
    int G = (N + 3) / 4;
    int SCAP = E + 8 * N;
    const int* src = ei;
    const int* dst = ei + E;

    char* w = (char*)d_ws;
    __hip_bfloat16* hb = (__hip_bfloat16*)w;   w += (size_t)N * HID * 2;
    __hip_bfloat16* xlb = (__hip_bfloat16*)w;  w += (size_t)N * HID * 2;
    __hip_bfloat16* xrb = (__hip_bfloat16*)w;  w += (size_t)N * HID * 2;
    unsigned* tmpp = (unsigned*)w;             w += (size_t)N * HID * 2;
    __hip_bfloat16* wz = (__hip_bfloat16*)w;   w += (size_t)7 * 16384 * 2;
    int4* slots = (int4*)w;       w += (size_t)SCAP * 16;
    // zero-region: deg, cursor, red (3 layers) contiguous -> ONE memset
    int* deg = (int*)w;           w += (size_t)N * 4;
    int* cursor = (int*)w;        w += (size_t)N * 4;
    float* red = (float*)w;       w += (size_t)NLAYER * RSLOTS * 2 * 4;
    int* slotbase = (int*)w;      w += (size_t)N * 4;
    int* groupstart = (int*)w;    w += (size_t)(G + 1) * 4;

    // ---- build + prep
    hipMemsetAsync(deg, 0, (size_t)(2 * N + NLAYER * RSLOTS * 2) * 4, stream);
    k_count<<<(E + 255) / 256, 256, 0, stream>>>(dst, deg, E);
    k_scan<<<1, 1024, 0, stream>>>(deg, groupstart, N, G);
    k_nodepad<<<(N + 255) / 256, 256, 0, stream>>>(deg, groupstart, slotbase, cursor, slots, N);
    k_fill2<<<(E + 255) / 256, 256, 0, stream>>>(src, dst, eattr, cursor, slots, E);
    k_wprep<<<7, 256, 0, stream>>>(Wl, Wr, Wout, wz);
    k_cast<<<(N * HID / 4 + 255) / 256, 256, 0, stream>>>(x, hb, N * HID);

    int gb = (N + 127) / 128;
    float M = (float)N * (float)HID;
    for (int l = 0; l < NLAYER; l++) {
        float* redl = red + (size_t)l * RSLOTS * 2;
        k_gemm_mfma<true><<<dim3(gb, 2), 256, 0, stream>>>(
            hb, wz + (size_t)(2 * l) * 16384, wz + (size_t)(2 * l + 1) * 16384,
            xlb, xrb, nullptr, N);
        k_aggregate<<<(N + 3) / 4, 256, 0, stream>>>(
            xlb, xrb, slots, deg, slotbase,
            We + (size_t)l * EDIM * HID, att + (size_t)l * NHEAD * CH, tmpp, redl, N);
        k_ln_gelu<<<((N * HID / 8) + 255) / 256, 256, 0, stream>>>(
            (const uint4*)tmpp, lnw + (size_t)l * HID, lnb + (size_t)l * HID, redl, M,
            (uint4*)hb, N * HID / 8);
    }
    k_gemm_mfma<false><<<dim3(gb, 1), 256, 0, stream>>>(
        hb, wz + (size_t)6 * 16384, wz + (size_t)6 * 16384, out, out, bout, N);
}

// Round 5
// 438.208 us; speedup vs baseline: 1.2110x; 1.0359x over previous
//
#include <hip/hip_runtime.h>
#include <hip/hip_bf16.h>
#include <math.h>

#define HID 128
#define NHEAD 4
#define CH 32
#define NLAYER 3
#define EDIM 3
#define EPSLN 1e-5f
#define SLOPE 0.2f
#define RSLOTS 1024   // LN-reduction slots (pairs) per layer
#define PAD_W -1e30f  // additive sentinel: exp2(part + PAD_W) == 0
#define LOG2E 1.4426950408889634f

typedef __bf16 bf16x8 __attribute__((ext_vector_type(8)));
typedef float f32x4 __attribute__((ext_vector_type(4)));
typedef float f32x2 __attribute__((ext_vector_type(2)));

__device__ __forceinline__ float bflo(unsigned d) { return __uint_as_float(d << 16); }
__device__ __forceinline__ float bfhi(unsigned d) { return __uint_as_float(d & 0xffff0000u); }

// 16-lane sum via row-DPP adds (no LDS pipe): xor1, xor2, half-mirror(^7), mirror(^15)
#define DPP_ADD(x, ctrl) \
    (x + __int_as_float(__builtin_amdgcn_update_dpp(0, __float_as_int(x), ctrl, 0xf, 0xf, true)))

// ---------------------------------------------------------------- degree count
__global__ void k_count(const int* __restrict__ dst, int* __restrict__ deg, int E) {
    int i = blockIdx.x * blockDim.x + threadIdx.x;
    if (i < E) atomicAdd(&deg[dst[i]], 1);
}

// ---------------------------------------------------------------- single-block scan
// Scans per-group totals where group value = sum_{j<4} pad4(deg[4g+j]).
__global__ __launch_bounds__(1024) void k_scan(const int* __restrict__ deg,
                                               int* __restrict__ outs,
                                               int N, int G) {
    __shared__ int sw[16];
    __shared__ int scarry;
    int tid = threadIdx.x, lane = tid & 63, wid = tid >> 6;
    if (tid == 0) scarry = 0;
    __syncthreads();
    for (int base = 0; base < G; base += 1024) {
        int i = base + tid;
        int v = 0;
        if (i < G) {
            int n0 = 4 * i;
            if (n0 + 3 < N) {
                int4 d4 = *(const int4*)&deg[n0];
                v = ((d4.x + 3) & ~3) + ((d4.y + 3) & ~3) +
                    ((d4.z + 3) & ~3) + ((d4.w + 3) & ~3);
            } else {
#pragma unroll
                for (int j = 0; j < 4; j++) {
                    int n = n0 + j;
                    if (n < N) v += (deg[n] + 3) & ~3;
                }
            }
        }
        int x = v;
#pragma unroll
        for (int o = 1; o < 64; o <<= 1) { int y = __shfl_up(x, o, 64); if (lane >= o) x += y; }
        if (lane == 63) sw[wid] = x;
        __syncthreads();
        int carry = scarry;
        if (tid < 16) {
            int s = sw[tid];
#pragma unroll
            for (int o = 1; o < 16; o <<= 1) { int y = __shfl_up(s, o, 64); if (tid >= o) s += y; }
            sw[tid] = s;
        }
        __syncthreads();
        int wofs = (wid == 0) ? 0 : sw[wid - 1];
        int incl = carry + wofs + x;
        if (i < G) outs[i] = incl - v;
        __syncthreads();
        if (tid == 0) scarry = carry + sw[15];
        __syncthreads();
    }
    if (tid == 0) outs[G] = scarry;
}

// ---------------------------------------------------------------- per-node base + pad init
// slotbase[i]=cursor[i]= groupstart[i>>2] + earlier nodes' pad4(deg) in group.
// Initializes ONLY the pad slots (deg..pad4-1): {src=-1, e=0}.
__global__ void k_nodepad(const int* __restrict__ deg, const int* __restrict__ groupstart,
                          int* __restrict__ slotbase, int* __restrict__ cursor,
                          int4* __restrict__ slots, int N) {
    int i = blockIdx.x * blockDim.x + threadIdx.x;
    if (i >= N) return;
    int g = i >> 2;
    int base = groupstart[g];
    int i0 = g * 4;
#pragma unroll
    for (int j = 0; j < 3; j++)
        if (i0 + j < i) base += (deg[i0 + j] + 3) & ~3;
    slotbase[i] = base;
    cursor[i] = base;
    int d = deg[i];
    int pd = (d + 3) & ~3;
    for (int j = d; j < pd; j++) slots[base + j] = make_int4(-1, 0, 0, 0);
}

// one 16B scattered store per edge: {src, e0, e1, e2}
__global__ void k_fill2(const int* __restrict__ src, const int* __restrict__ dst,
                        const float* __restrict__ eattr, int* __restrict__ cursor,
                        int4* __restrict__ slots, int E) {
    int i = blockIdx.x * blockDim.x + threadIdx.x;
    if (i < E) {
        int n = dst[i];
        int slot = atomicAdd(&cursor[n], 1);
        slots[slot] = make_int4(src[i], __float_as_int(eattr[3 * i]),
                                __float_as_int(eattr[3 * i + 1]),
                                __float_as_int(eattr[3 * i + 2]));
    }
}

// ---------------------------------------------------------------- weight prep
// bf16 + MFMA B-fragment swizzle: wz[((s*8+n)*64+q)*8+j] = W[(s*32+(q>>4)*8+j)*128 + n*16+(q&15)]
__global__ __launch_bounds__(256) void k_wprep(const float* __restrict__ Wl,
                                               const float* __restrict__ Wr,
                                               const float* __restrict__ Wout,
                                               __hip_bfloat16* __restrict__ wz) {
    int b = blockIdx.x;  // 0..6: l0Wl,l0Wr,l1Wl,l1Wr,l2Wl,l2Wr,Wout
    const float* src = (b < 6) ? ((b & 1) ? Wr + (size_t)(b >> 1) * 16384
                                          : Wl + (size_t)(b >> 1) * 16384)
                               : Wout;
    for (int t = threadIdx.x; t < 16384; t += 256) {
        int j = t & 7, q = (t >> 3) & 63, n = (t >> 9) & 7, s = t >> 12;
        int k = s * 32 + (q >> 4) * 8 + j;
        int c = n * 16 + (q & 15);
        wz[(size_t)b * 16384 + t] = __float2bfloat16(src[k * 128 + c]);
    }
}

__global__ __launch_bounds__(256) void k_cast(const float* __restrict__ in,
                                              __hip_bfloat16* __restrict__ out, int n) {
    int i = (blockIdx.x * 256 + threadIdx.x) * 4;
    if (i < n) {
        float4 v = *(const float4*)&in[i];
        __hip_bfloat16 o[4] = {__float2bfloat16(v.x), __float2bfloat16(v.y),
                               __float2bfloat16(v.z), __float2bfloat16(v.w)};
        *(ushort4*)&out[i] = *(ushort4*)o;
    }
}

// ---------------------------------------------------------------- MFMA GEMM
// Y = Xb(bf16) @ W(bf16 pre-swizzled); out bf16 (layers) or fp32+bias (final).
template <bool BF16OUT>
__global__ __launch_bounds__(256) void k_gemm_mfma(const __hip_bfloat16* __restrict__ Xb,
                                                   const __hip_bfloat16* __restrict__ Wz0,
                                                   const __hip_bfloat16* __restrict__ Wz1,
                                                   void* __restrict__ Y0v,
                                                   void* __restrict__ Y1v,
                                                   const float* __restrict__ bias, int N) {
    __shared__ __hip_bfloat16 sW[16384];  // 32 KB
    const __hip_bfloat16* Wz = blockIdx.y ? Wz1 : Wz0;
    void* Yv = blockIdx.y ? Y1v : Y0v;
    int tid = threadIdx.x;
    {
        const float4* s4 = (const float4*)Wz;
        float4* d4 = (float4*)sW;
#pragma unroll
        for (int i = 0; i < 8; i++) d4[tid + 256 * i] = s4[tid + 256 * i];
    }
    __syncthreads();

    int wv = tid >> 6, lane = tid & 63;
    int quad = lane >> 4, l16 = lane & 15;
    int mbase = blockIdx.x * 128 + wv * 32;

    f32x4 acc[2][8];
#pragma unroll
    for (int mt = 0; mt < 2; mt++)
#pragma unroll
        for (int n = 0; n < 8; n++) acc[mt][n] = (f32x4){0.f, 0.f, 0.f, 0.f};

#pragma unroll
    for (int s = 0; s < 4; s++) {
        bf16x8 a[2];
#pragma unroll
        for (int mt = 0; mt < 2; mt++) {
            int row = mbase + mt * 16 + l16;
            row = (row < N) ? row : (N - 1);
            a[mt] = *(const bf16x8*)&Xb[(size_t)row * HID + s * 32 + quad * 8];
        }
#pragma unroll
        for (int n = 0; n < 8; n++) {
            bf16x8 b = *(const bf16x8*)&sW[((s * 8 + n) * 64 + lane) * 8];
            acc[0][n] = __builtin_amdgcn_mfma_f32_16x16x32_bf16(a[0], b, acc[0][n], 0, 0, 0);
            acc[1][n] = __builtin_amdgcn_mfma_f32_16x16x32_bf16(a[1], b, acc[1][n], 0, 0, 0);
        }
    }

    float bv[8];
#pragma unroll
    for (int n = 0; n < 8; n++) bv[n] = bias ? bias[n * 16 + l16] : 0.f;

#pragma unroll
    for (int mt = 0; mt < 2; mt++)
#pragma unroll
        for (int reg = 0; reg < 4; reg++) {
            int row = mbase + mt * 16 + quad * 4 + reg;
            if (row < N) {
                if (BF16OUT) {
                    __hip_bfloat16* yp = (__hip_bfloat16*)Yv + (size_t)row * HID + l16;
#pragma unroll
                    for (int n = 0; n < 8; n++) yp[n * 16] = __float2bfloat16(acc[mt][n][reg]);
                } else {
                    float* yp = (float*)Yv + (size_t)row * HID + l16;
#pragma unroll
                    for (int n = 0; n < 8; n++) yp[n * 16] = acc[mt][n][reg] + bv[n];
                }
            }
        }
}

// ---------------------------------------------------------------- GATv2 aggregate (per-node)
// One wave per node: steps = ceil(deg/4), 4 edges of the SAME node per step.
// Slot record: int4 {src(-1=pad), e0, e1, e2}. att pre-scaled by log2e -> v_exp direct.
// Channel math in f32x2 (v_pk_* packed fp32); 16-lane reduce via row-DPP adds.
__global__ __launch_bounds__(256) void k_aggregate(const __hip_bfloat16* __restrict__ xlb,
                                                   const __hip_bfloat16* __restrict__ xrb,
                                                   const int4* __restrict__ slots,
                                                   const int* __restrict__ deg,
                                                   const int* __restrict__ slotbase,
                                                   const float* __restrict__ We,
                                                   const float* __restrict__ att,
                                                   unsigned* __restrict__ tmpp,
                                                   float* __restrict__ red, int N) {
    int wid = threadIdx.x >> 6;
    int lane = threadIdx.x & 63;
    int node = blockIdx.x * 4 + wid;
    if (node >= N) return;
    int c0 = lane * 2;
    int head = lane >> 4;

    f32x2 we0, we1, we2;
    { float2 t = *(const float2*)&We[c0];            we0 = (f32x2){t.x, t.y}; }
    { float2 t = *(const float2*)&We[HID + c0];      we1 = (f32x2){t.x, t.y}; }
    { float2 t = *(const float2*)&We[2 * HID + c0];  we2 = (f32x2){t.x, t.y}; }
    float at0 = att[head * CH + (c0 & 31)] * LOG2E;        // fold log2e: exp2(m.at') == exp(m.at)
    float at1 = att[head * CH + (c0 & 31) + 1] * LOG2E;

    int base = __builtin_amdgcn_readfirstlane(slotbase[node]);
    int steps = __builtin_amdgcn_readfirstlane((deg[node] + 3) >> 2);

    unsigned dxr = *(const unsigned*)&xrb[(size_t)node * HID + c0];
    f32x2 xr2 = (f32x2){bflo(dxr), bfhi(dxr)};

    float l = 0.f;
    f32x2 Av = (f32x2){0.f, 0.f};

    const int4* vp = slots + base;

    for (int t = 0; t < steps; t++) {
        int4 v[4];
#pragma unroll
        for (int j = 0; j < 4; j++) v[j] = vp[4 * t + j];
        unsigned dv[4];
#pragma unroll
        for (int j = 0; j < 4; j++) {
            int si = max(v[j].x, 0);
            dv[j] = *(const unsigned*)&xlb[(size_t)si * HID + c0];  // 4 indep gathers, 4B each
        }
#pragma unroll
        for (int j = 0; j < 4; j++) {
            float e0 = __int_as_float(v[j].y);
            float e1 = __int_as_float(v[j].z);
            float e2 = __int_as_float(v[j].w);
            float padw = (v[j].x < 0) ? PAD_W : 0.f;
            f32x2 xv = (f32x2){bflo(dv[j]), bfhi(dv[j])};
            // m = xv + xr + e·We, fully fused: 1 pk_add + 3 pk_fma
            f32x2 m = __builtin_elementwise_fma(we2, (f32x2)e2, xv + xr2);
            m = __builtin_elementwise_fma(we1, (f32x2)e1, m);
            m = __builtin_elementwise_fma(we0, (f32x2)e0, m);
            // leakyrelu (slope<1): pk_mul + 2 max
            f32x2 ms = m * SLOPE;
            m.x = fmaxf(m.x, ms.x);
            m.y = fmaxf(m.y, ms.y);
            float part = fmaf(m.x, at0, m.y * at1);
            // 16-lane sum on the VALU via DPP (xor1, xor2, ^7, ^15)
            part = DPP_ADD(part, 0xB1);   // quad_perm [1,0,3,2]
            part = DPP_ADD(part, 0x4E);   // quad_perm [2,3,0,1]
            part = DPP_ADD(part, 0x141);  // row_half_mirror (^7)
            part = DPP_ADD(part, 0x140);  // row_mirror (^15)
            float p = __builtin_amdgcn_exp2f(part + padw);  // padding: exp2(-1e30)=0
            l += p;
            Av = __builtin_elementwise_fma((f32x2)p, xv, Av);
        }
    }

    float inv = 1.f / (l + 1e-16f);
    f32x2 o2 = Av * inv;
    __hip_bfloat16 pk[2] = {__float2bfloat16(o2.x), __float2bfloat16(o2.y)};
    tmpp[(size_t)node * (HID / 2) + lane] = *(unsigned*)pk;

    float ssum = o2.x + o2.y;             // LN stats from pre-rounded fp32
    float ssq = fmaf(o2.x, o2.x, o2.y * o2.y);
#pragma unroll
    for (int o = 32; o >= 1; o >>= 1) { ssum += __shfl_xor(ssum, o); ssq += __shfl_xor(ssq, o); }
    if (lane == 0) {
        int slot = (node & (RSLOTS - 1)) * 2;
        atomicAdd(&red[slot], ssum);
        atomicAdd(&red[slot + 1], ssq);
    }
}

// ---------------------------------------------------------------- LN + gelu (bf16 in/out)
// Each block redundantly reduces the layer's red[] (8 KB, L2-hot) -> no separate finish kernel.
__global__ __launch_bounds__(256) void k_ln_gelu(const uint4* __restrict__ in4,
                                                 const float* __restrict__ w,
                                                 const float* __restrict__ b,
                                                 const float* __restrict__ red,
                                                 float M,
                                                 uint4* __restrict__ out4, int n8) {
    __shared__ float ls[8];
    int tid = threadIdx.x;
    float s = 0.f, q = 0.f;
    const float2* r2 = (const float2*)red;
    for (int i = tid; i < RSLOTS; i += 256) { float2 rv = r2[i]; s += rv.x; q += rv.y; }
#pragma unroll
    for (int o = 32; o >= 1; o >>= 1) { s += __shfl_xor(s, o); q += __shfl_xor(q, o); }
    if ((tid & 63) == 0) { ls[(tid >> 6) * 2] = s; ls[(tid >> 6) * 2 + 1] = q; }
    __syncthreads();
    float S = ls[0] + ls[2] + ls[4] + ls[6];
    float Q = ls[1] + ls[3] + ls[5] + ls[7];
    float mean = S / M;
    float inv = rsqrtf(Q / M - mean * mean + EPSLN);

    int i = blockIdx.x * blockDim.x + tid;
    if (i >= n8) return;
    uint4 v = in4[i];
    int col = (i * 8) & 127;
    float4 w0 = *(const float4*)&w[col], w1 = *(const float4*)&w[col + 4];
    float4 b0 = *(const float4*)&b[col], b1 = *(const float4*)&b[col + 4];
    float r[8] = {bflo(v.x), bfhi(v.x), bflo(v.y), bfhi(v.y),
                  bflo(v.z), bfhi(v.z), bflo(v.w), bfhi(v.w)};
    float wr[8] = {w0.x, w0.y, w0.z, w0.w, w1.x, w1.y, w1.z, w1.w};
    float br[8] = {b0.x, b0.y, b0.z, b0.w, b1.x, b1.y, b1.z, b1.w};
    __hip_bfloat16 o[8];
#pragma unroll
    for (int j = 0; j < 8; j++) {
        float t = fmaf((r[j] - mean) * inv, wr[j], br[j]);
        o[j] = __float2bfloat16(0.5f * t * (1.f + erff(t * 0.70710678118654752f)));
    }
    out4[i] = *(uint4*)o;
}

// ---------------------------------------------------------------- launch
extern "C" void kernel_launch(void* const* d_in, const int* in_sizes, int n_in,
                              void* d_out, int out_size, void* d_ws, size_t ws_size,
                              hipStream_t stream) {
    const float* x = (const float*)d_in[0];
    const int* ei = (const int*)d_in[1];
    const float* eattr = (const float*)d_in[2];
    const float* Wl = (const float*)d_in[3];
    const float* Wr = (const float*)d_in[4];
    const float* We = (const float*)d_in[5];
    const float* att = (const float*)d_in[6];
    const float* lnw = (const float*)d_in[7];
    const float* lnb = (const float*)d_in[8];
    const float* Wout = (const float*)d_in[9];
    const float* bout = (const float*)d_in[10];
    float* out = (float*)d_out;

    int N = in_sizes[0] / HID;
    int E = in_sizes[1] / 2;
    int G = (N + 3) / 4;
    int SCAP = E + 8 * N;
    const int* src = ei;
    const int* dst = ei + E;

    char* w = (char*)d_ws;
    __hip_bfloat16* hb = (__hip_bfloat16*)w;   w += (size_t)N * HID * 2;
    __hip_bfloat16* xlb = (__hip_bfloat16*)w;  w += (size_t)N * HID * 2;
    __hip_bfloat16* xrb = (__hip_bfloat16*)w;  w += (size_t)N * HID * 2;
    unsigned* tmpp = (unsigned*)w;             w += (size_t)N * HID * 2;
    __hip_bfloat16* wz = (__hip_bfloat16*)w;   w += (size_t)7 * 16384 * 2;
    int4* slots = (int4*)w;       w += (size_t)SCAP * 16;
    // zero-region: deg, cursor, red (3 layers) contiguous -> ONE memset
    int* deg = (int*)w;           w += (size_t)N * 4;
    int* cursor = (int*)w;        w += (size_t)N * 4;
    float* red = (float*)w;       w += (size_t)NLAYER * RSLOTS * 2 * 4;
    int* slotbase = (int*)w;      w += (size_t)N * 4;
    int* groupstart = (int*)w;    w += (size_t)(G + 1) * 4;

    // ---- build + prep
    hipMemsetAsync(deg, 0, (size_t)(2 * N + NLAYER * RSLOTS * 2) * 4, stream);
    k_count<<<(E + 255) / 256, 256, 0, stream>>>(dst, deg, E);
    k_scan<<<1, 1024, 0, stream>>>(deg, groupstart, N, G);
    k_nodepad<<<(N + 255) / 256, 256, 0, stream>>>(deg, groupstart, slotbase, cursor, slots, N);
    k_fill2<<<(E + 255) / 256, 256, 0, stream>>>(src, dst, eattr, cursor, slots, E);
    k_wprep<<<7, 256, 0, stream>>>(Wl, Wr, Wout, wz);
    k_cast<<<(N * HID / 4 + 255) / 256, 256, 0, stream>>>(x, hb, N * HID);

    int gb = (N + 127) / 128;
    float M = (float)N * (float)HID;
    for (int l = 0; l < NLAYER; l++) {
        float* redl = red + (size_t)l * RSLOTS * 2;
        k_gemm_mfma<true><<<dim3(gb, 2), 256, 0, stream>>>(
            hb, wz + (size_t)(2 * l) * 16384, wz + (size_t)(2 * l + 1) * 16384,
            xlb, xrb, nullptr, N);
        k_aggregate<<<(N + 3) / 4, 256, 0, stream>>>(
            xlb, xrb, slots, deg, slotbase,
            We + (size_t)l * EDIM * HID, att + (size_t)l * NHEAD * CH, tmpp, redl, N);
        k_ln_gelu<<<((N * HID / 8) + 255) / 256, 256, 0, stream>>>(
            (const uint4*)tmpp, lnw + (size_t)l * HID, lnb + (size_t)l * HID, redl, M,
            (uint4*)hb, N * HID / 8);
    }
    k_gemm_mfma<false><<<dim3(gb, 1), 256, 0, stream>>>(
        hb, wz + (size_t)6 * 16384, wz + (size_t)6 * 16384, out, out, bout, N);
}